// Round 1
// baseline (1481.568 us; speedup 1.0000x reference)
//
#include <hip/hip_runtime.h>

#define NN 60000
#define EE 1200000

__device__ __forceinline__ float leakyf(float x){ return x >= 0.f ? x : 0.2f*x; }
__device__ __forceinline__ float eluf(float x){ return x > 0.f ? x : expm1f(x); }

// ---- CSR build ----
__global__ void k_count(const int* __restrict__ dst, int* __restrict__ counts){
    int e = blockIdx.x*blockDim.x + threadIdx.x;
    if (e < EE) atomicAdd(&counts[dst[e]], 1);
}

__global__ __launch_bounds__(1024) void k_scan(const int* __restrict__ counts,
                                               int* __restrict__ row_ptr){
    __shared__ int ssum[1024];
    int t = threadIdx.x;
    const int per = (NN + 1023)/1024;
    int begin = t*per; if (begin > NN) begin = NN;
    int end = begin+per; if (end > NN) end = NN;
    int s = 0;
    for (int i=begin;i<end;i++) s += counts[i];
    ssum[t] = s;
    __syncthreads();
    for (int off=1; off<1024; off<<=1){
        int other = (t >= off) ? ssum[t-off] : 0;
        __syncthreads();
        ssum[t] += other;
        __syncthreads();
    }
    int run = ssum[t] - s;   // exclusive prefix of this thread's chunk
    for (int i=begin;i<end;i++){ row_ptr[i] = run; run += counts[i]; }
    if (t == 1023) row_ptr[NN] = ssum[1023];
}

__global__ void k_scatter(const int* __restrict__ src, const int* __restrict__ dst,
                          const int* __restrict__ row_ptr, int* __restrict__ cursor,
                          int* __restrict__ col){
    int e = blockIdx.x*blockDim.x + threadIdx.x;
    if (e < EE){
        int d = dst[e];
        int p = row_ptr[d] + atomicAdd(&cursor[d], 1);
        col[p] = src[e];
    }
}

// ---- GAT linear: xw = x @ gat_w.T  [N,128]; a_src/a_dst [N,4] ----
__global__ __launch_bounds__(128) void k_xw(const float* __restrict__ x,
        const float* __restrict__ w, const float* __restrict__ att_s,
        const float* __restrict__ att_d, float* __restrict__ xw,
        float* __restrict__ a_src, float* __restrict__ a_dst){
    int n = blockIdx.x, o = threadIdx.x;
    __shared__ float xs[64];
    if (o < 64) xs[o] = x[n*64 + o];
    __syncthreads();
    float acc = 0.f;
    const float* wr = w + o*64;
    #pragma unroll
    for (int k=0;k<64;k++) acc += xs[k]*wr[k];
    xw[(size_t)n*128 + o] = acc;
    int h = o >> 5, c = o & 31;
    float vs = acc * att_s[h*32 + c];
    float vd = acc * att_d[h*32 + c];
    #pragma unroll
    for (int d2=1; d2<32; d2<<=1){ vs += __shfl_xor(vs, d2); vd += __shfl_xor(vd, d2); }
    if (c == 0){ a_src[n*4 + h] = vs; a_dst[n*4 + h] = vd; }
}

// ---- GAT aggregation + ELU + BN1 -> h1 [N,128] ----
__global__ __launch_bounds__(128) void k_gat(const int* __restrict__ row_ptr,
        const int* __restrict__ col, const float* __restrict__ a_src,
        const float* __restrict__ a_dst, const float* __restrict__ xw,
        const float* __restrict__ gb,
        const float* __restrict__ g1, const float* __restrict__ b1,
        const float* __restrict__ m1, const float* __restrict__ v1,
        float* __restrict__ h1){
    int n = blockIdx.x, t = threadIdx.x;
    int lane = t & 63, wv = t >> 6;
    int r0 = row_ptr[n], deg = row_ptr[n+1] - r0;
    __shared__ float red[2][4];
    __shared__ float MXs[4], Ss[4];

    int ha = t & 3;
    float adh_a = a_dst[n*4 + ha];
    float selfl = leakyf(a_src[n*4 + ha] + adh_a);

    // phase A: per-head max (self-loop included in every thread's init)
    float mx = selfl;
    for (int i = t>>2; i < deg; i += 32)
        mx = fmaxf(mx, leakyf(a_src[col[r0+i]*4 + ha] + adh_a));
    #pragma unroll
    for (int d2=4; d2<64; d2<<=1) mx = fmaxf(mx, __shfl_xor(mx, d2));
    if (lane < 4) red[wv][lane] = mx;
    __syncthreads();
    if (t < 4) MXs[t] = fmaxf(red[0][t], red[1][t]);
    __syncthreads();
    float MX = MXs[ha];

    // phase B: expsum (self term added once per head by t<4)
    float sm = (t < 4) ? __expf(selfl - MX) : 0.f;
    for (int i = t>>2; i < deg; i += 32)
        sm += __expf(leakyf(a_src[col[r0+i]*4 + ha] + adh_a) - MX);
    #pragma unroll
    for (int d2=4; d2<64; d2<<=1) sm += __shfl_xor(sm, d2);
    if (lane < 4) red[wv][lane] = sm;
    __syncthreads();
    if (t < 4) Ss[t] = red[0][t] + red[1][t] + 1e-16f;
    __syncthreads();

    // phase C: weighted gather; thread t owns output channel o=t
    int o = t, h = o >> 5;
    float MXh = MXs[h], Sinv = 1.f / Ss[h];
    float adh = a_dst[n*4 + h];
    float al_self = __expf(leakyf(a_src[n*4 + h] + adh) - MXh) * Sinv;
    float acc = xw[(size_t)n*128 + o] * al_self;
    for (int i = 0; i < deg; i++){
        int s = col[r0+i];
        float al = __expf(leakyf(a_src[s*4 + h] + adh) - MXh) * Sinv;
        acc += xw[(size_t)s*128 + o] * al;
    }
    acc += gb[o];
    acc = eluf(acc);
    acc = (acc - m1[o]) * rsqrtf(v1[o] + 1e-5f) * g1[o] + b1[o];
    h1[(size_t)n*128 + o] = acc;
}

// ---- SAGE: mean-gather + 2 dots + ELU + BN2 -> h2 [N,64] ----
__global__ __launch_bounds__(128) void k_sage(const int* __restrict__ row_ptr,
        const int* __restrict__ col, const float* __restrict__ h1,
        const float* __restrict__ wl, const float* __restrict__ bl,
        const float* __restrict__ wr,
        const float* __restrict__ g2, const float* __restrict__ b2,
        const float* __restrict__ m2, const float* __restrict__ v2,
        float* __restrict__ h2){
    int n = blockIdx.x, t = threadIdx.x;
    int r0 = row_ptr[n], deg = row_ptr[n+1] - r0;
    __shared__ float mean_s[128], self_s[128];
    float acc = 0.f;
    for (int i = 0; i < deg; i++) acc += h1[(size_t)col[r0+i]*128 + t];
    mean_s[t] = (deg > 0) ? acc / (float)deg : 0.f;
    self_s[t] = h1[(size_t)n*128 + t];
    __syncthreads();
    if (t < 64){
        float o_acc = bl[t];
        const float* wlr = wl + t*128;
        const float* wrr = wr + t*128;
        #pragma unroll 4
        for (int k=0;k<128;k++) o_acc += mean_s[k]*wlr[k] + self_s[k]*wrr[k];
        o_acc = eluf(o_acc);
        o_acc = (o_acc - m2[t]) * rsqrtf(v2[t] + 1e-5f) * g2[t] + b2[t];
        h2[(size_t)n*64 + t] = o_acc;
    }
}

// ---- GCN: hw = h2 @ gcn_w.T  [N,32] ----
__global__ void k_hw(const float* __restrict__ h2, const float* __restrict__ w,
                     float* __restrict__ hw){
    int idx = blockIdx.x*blockDim.x + threadIdx.x;
    if (idx >= NN*32) return;
    int n = idx >> 5, o = idx & 31;
    const float* hr = h2 + (size_t)n*64;
    const float* wr = w + o*64;
    float acc = 0.f;
    #pragma unroll
    for (int k=0;k<64;k++) acc += hr[k]*wr[k];
    hw[idx] = acc;
}

__global__ void k_dinv(const int* __restrict__ row_ptr, float* __restrict__ dinv){
    int n = blockIdx.x*blockDim.x + threadIdx.x;
    if (n < NN) dinv[n] = rsqrtf((float)(row_ptr[n+1] - row_ptr[n] + 1));
}

// ---- GCN aggregation + ELU + BN3 -> out [N,32] ----
__global__ __launch_bounds__(64) void k_gcn(const int* __restrict__ row_ptr,
        const int* __restrict__ col, const float* __restrict__ hw,
        const float* __restrict__ dinv, const float* __restrict__ gb,
        const float* __restrict__ g3, const float* __restrict__ b3,
        const float* __restrict__ m3, const float* __restrict__ v3,
        float* __restrict__ out){
    int n = blockIdx.x;
    int lane = threadIdx.x;
    int o = lane & 31, half = lane >> 5;
    int r0 = row_ptr[n], deg = row_ptr[n+1] - r0;
    float dn = dinv[n];
    float acc = 0.f;
    for (int i = half; i < deg; i += 2){
        int s = col[r0+i];
        acc += dinv[s] * hw[(size_t)s*32 + o];
    }
    acc += __shfl_xor(acc, 32);
    float tot = acc * dn + dn*dn*hw[(size_t)n*32 + o];
    if (half == 0){
        tot += gb[o];
        tot = eluf(tot);
        tot = (tot - m3[o]) * rsqrtf(v3[o] + 1e-5f) * g3[o] + b3[o];
        out[(size_t)n*32 + o] = tot;
    }
}

extern "C" void kernel_launch(void* const* d_in, const int* in_sizes, int n_in,
                              void* d_out, int out_size, void* d_ws, size_t ws_size,
                              hipStream_t stream)
{
    const float* x     = (const float*)d_in[0];
    const int*   ei    = (const int*)d_in[1];
    const float* gat_w = (const float*)d_in[2];
    const float* att_s = (const float*)d_in[3];
    const float* att_d = (const float*)d_in[4];
    const float* gat_b = (const float*)d_in[5];
    const float* bn1g = (const float*)d_in[6],  *bn1b = (const float*)d_in[7];
    const float* bn1m = (const float*)d_in[8],  *bn1v = (const float*)d_in[9];
    const float* sage_wl = (const float*)d_in[10];
    const float* sage_bl = (const float*)d_in[11];
    const float* sage_wr = (const float*)d_in[12];
    const float* bn2g = (const float*)d_in[13], *bn2b = (const float*)d_in[14];
    const float* bn2m = (const float*)d_in[15], *bn2v = (const float*)d_in[16];
    const float* gcn_w = (const float*)d_in[17];
    const float* gcn_b = (const float*)d_in[18];
    const float* bn3g = (const float*)d_in[19], *bn3b = (const float*)d_in[20];
    const float* bn3m = (const float*)d_in[21], *bn3v = (const float*)d_in[22];

    const int* src  = ei;
    const int* dstp = ei + EE;

    float* f    = (float*)d_ws;
    float* xw   = f;                          // N*128 ; reused later: h2 (N*64), hw (N*32)
    float* h1   = f + (size_t)NN*128;         // N*128
    float* a_s  = h1 + (size_t)NN*128;        // N*4
    float* a_d  = a_s + (size_t)NN*4;         // N*4
    float* dinv = a_d + (size_t)NN*4;         // N
    int* row_ptr = (int*)(dinv + NN);         // N+1
    int* counts  = row_ptr + (NN+1);          // N
    int* col     = counts + NN;               // E
    float* h2 = xw;                           // alias (xw dead after k_gat)
    float* hw = xw + (size_t)NN*64;
    float* out = (float*)d_out;

    hipMemsetAsync(counts, 0, NN*sizeof(int), stream);
    k_count<<<(EE+255)/256, 256, 0, stream>>>(dstp, counts);
    k_scan<<<1, 1024, 0, stream>>>(counts, row_ptr);
    hipMemsetAsync(counts, 0, NN*sizeof(int), stream);
    k_scatter<<<(EE+255)/256, 256, 0, stream>>>(src, dstp, row_ptr, counts, col);

    k_xw<<<NN, 128, 0, stream>>>(x, gat_w, att_s, att_d, xw, a_s, a_d);
    k_gat<<<NN, 128, 0, stream>>>(row_ptr, col, a_s, a_d, xw, gat_b,
                                  bn1g, bn1b, bn1m, bn1v, h1);
    k_sage<<<NN, 128, 0, stream>>>(row_ptr, col, h1, sage_wl, sage_bl, sage_wr,
                                   bn2g, bn2b, bn2m, bn2v, h2);
    k_hw<<<(NN*32+255)/256, 256, 0, stream>>>(h2, gcn_w, hw);
    k_dinv<<<(NN+255)/256, 256, 0, stream>>>(row_ptr, dinv);
    k_gcn<<<NN, 64, 0, stream>>>(row_ptr, col, hw, dinv, gcn_b,
                                 bn3g, bn3b, bn3m, bn3v, out);
}

// Round 4
// 839.567 us; speedup vs baseline: 1.7647x; 1.7647x over previous
//
#include <hip/hip_runtime.h>

#define NN 60000
#define EE 1200000

__device__ __forceinline__ float leakyf(float x){ return x >= 0.f ? x : 0.2f*x; }
__device__ __forceinline__ float eluf(float x){ return x > 0.f ? x : expm1f(x); }

// ---- CSR build ----
__global__ void k_count(const int* __restrict__ dst, int* __restrict__ counts){
    int e = blockIdx.x*blockDim.x + threadIdx.x;
    if (e < EE) atomicAdd(&counts[dst[e]], 1);
}

__global__ __launch_bounds__(1024) void k_scan(const int* __restrict__ counts,
                                               int* __restrict__ row_ptr){
    __shared__ int ssum[1024];
    int t = threadIdx.x;
    const int per = (NN + 1023)/1024;
    int begin = t*per; if (begin > NN) begin = NN;
    int end = begin+per; if (end > NN) end = NN;
    int s = 0;
    for (int i=begin;i<end;i++) s += counts[i];
    ssum[t] = s;
    __syncthreads();
    for (int off=1; off<1024; off<<=1){
        int other = (t >= off) ? ssum[t-off] : 0;
        __syncthreads();
        ssum[t] += other;
        __syncthreads();
    }
    int run = ssum[t] - s;
    for (int i=begin;i<end;i++){ row_ptr[i] = run; run += counts[i]; }
    if (t == 1023) row_ptr[NN] = ssum[1023];
}

__global__ void k_scatter(const int* __restrict__ src, const int* __restrict__ dst,
                          const int* __restrict__ row_ptr, int* __restrict__ cursor,
                          int* __restrict__ col){
    int e = blockIdx.x*blockDim.x + threadIdx.x;
    if (e < EE){
        int d = dst[e];
        int p = row_ptr[d] + atomicAdd(&cursor[d], 1);
        col[p] = src[e];
    }
}

// ---- GAT linear: xw = x @ gat_w.T [N,128]; a_src/a_dst [N,4]. LDS-staged W ----
#define NTXW 16
__global__ __launch_bounds__(256) void k_xw(const float* __restrict__ x,
        const float* __restrict__ w, const float* __restrict__ att_s,
        const float* __restrict__ att_d, float* __restrict__ xw,
        float* __restrict__ a_src, float* __restrict__ a_dst){
    __shared__ float ws[128][65];
    __shared__ float xs[NTXW][65];
    int t = threadIdx.x;
    for (int idx = t; idx < 128*64; idx += 256){
        int r = idx >> 6, c = idx & 63;
        ws[r][c] = w[idx];
    }
    int o = t & 127;
    float as = att_s[o], ad = att_d[o];
    int h = o >> 5, c = o & 31;
    for (int tile = blockIdx.x; tile < NN/NTXW; tile += gridDim.x){
        int nb = tile * NTXW;
        __syncthreads();
        for (int idx = t; idx < NTXW*64; idx += 256){
            int r = idx >> 6, cc = idx & 63;
            xs[r][cc] = x[(size_t)(nb + r)*64 + cc];
        }
        __syncthreads();
        #pragma unroll
        for (int pass = 0; pass < NTXW/2; ++pass){
            int nd = pass*2 + (t >> 7);
            float acc = 0.f;
            #pragma unroll
            for (int k = 0; k < 64; k++) acc += xs[nd][k]*ws[o][k];
            int n = nb + nd;
            xw[(size_t)n*128 + o] = acc;
            float vs = acc*as, vd = acc*ad;
            #pragma unroll
            for (int d2 = 1; d2 < 32; d2 <<= 1){ vs += __shfl_xor(vs,d2); vd += __shfl_xor(vd,d2); }
            if (c == 0){ a_src[n*4 + h] = vs; a_dst[n*4 + h] = vd; }
        }
    }
}

// ---- GAT aggregation + ELU + BN1 -> h1 [N,128]; per-edge alpha computed once ----
__global__ __launch_bounds__(128) void k_gat(const int* __restrict__ row_ptr,
        const int* __restrict__ col, const float* __restrict__ a_src,
        const float* __restrict__ a_dst, const float* __restrict__ xw,
        const float* __restrict__ gb,
        const float* __restrict__ g1, const float* __restrict__ b1,
        const float* __restrict__ m1, const float* __restrict__ v1,
        float* __restrict__ h1){
    int n = blockIdx.x, t = threadIdx.x;
    int lane = t & 63, wv = t >> 6;
    int r0 = row_ptr[n], deg = row_ptr[n+1] - r0;
    __shared__ float red[2][4];
    __shared__ float MXs[4], Ss[4], Sinv_s[4];
    __shared__ float alpha_s[32][4];
    __shared__ int col_s[32];

    int ha = t & 3;
    float adh_a = a_dst[n*4 + ha];
    float selfl = leakyf(a_src[n*4 + ha] + adh_a);

    // phase A: per-head max
    float mx = selfl;
    for (int i = t>>2; i < deg; i += 32)
        mx = fmaxf(mx, leakyf(a_src[col[r0+i]*4 + ha] + adh_a));
    #pragma unroll
    for (int d2=4; d2<64; d2<<=1) mx = fmaxf(mx, __shfl_xor(mx, d2));
    if (lane < 4) red[wv][lane] = mx;
    __syncthreads();
    if (t < 4) MXs[t] = fmaxf(red[0][t], red[1][t]);
    __syncthreads();
    float MX = MXs[ha];

    // phase B: expsum
    float sm = (t < 4) ? __expf(selfl - MX) : 0.f;
    for (int i = t>>2; i < deg; i += 32)
        sm += __expf(leakyf(a_src[col[r0+i]*4 + ha] + adh_a) - MX);
    #pragma unroll
    for (int d2=4; d2<64; d2<<=1) sm += __shfl_xor(sm, d2);
    if (lane < 4) red[wv][lane] = sm;
    __syncthreads();
    if (t < 4){ float S = red[0][t] + red[1][t] + 1e-16f; Ss[t] = S; Sinv_s[t] = 1.f/S; }
    __syncthreads();

    // phase C: chunked alpha + coalesced row gather; thread t owns channel o=t
    int o = t, h = o >> 5;
    float MXh = MXs[h], Sinv = Sinv_s[h];
    float al_self = __expf(leakyf(a_src[n*4 + h] + a_dst[n*4 + h]) - MXh) * Sinv;
    float acc = xw[(size_t)n*128 + o] * al_self;
    int e4 = t >> 2;
    for (int base = 0; base < deg; base += 32){
        int cnt = min(32, deg - base);
        __syncthreads();
        if (e4 < cnt){
            int s = col[r0 + base + e4];
            if (ha == 0) col_s[e4] = s;
            alpha_s[e4][ha] = __expf(leakyf(a_src[s*4 + ha] + adh_a) - MXs[ha]) * Sinv_s[ha];
        }
        __syncthreads();
        #pragma unroll 2
        for (int i = 0; i < cnt; i++)
            acc += xw[(size_t)col_s[i]*128 + o] * alpha_s[i][h];
    }
    acc += gb[o];
    acc = eluf(acc);
    acc = (acc - m1[o]) * rsqrtf(v1[o] + 1e-5f) * g1[o] + b1[o];
    h1[(size_t)n*128 + o] = acc;
}

// ---- SAGE fused: gather-mean + transform + ELU + BN2 -> h2 [N,64] ----
__global__ __launch_bounds__(256) void k_sage(const int* __restrict__ row_ptr,
        const int* __restrict__ col, const float* __restrict__ h1,
        const float* __restrict__ wl, const float* __restrict__ bl,
        const float* __restrict__ wr,
        const float* __restrict__ g2, const float* __restrict__ b2,
        const float* __restrict__ m2, const float* __restrict__ v2,
        float* __restrict__ h2){
    __shared__ float wls[64][129];
    __shared__ float wrs[64][129];
    __shared__ float mean_s[4][130];
    __shared__ float self_s[4][130];
    int t = threadIdx.x;
    for (int idx = t; idx < 64*128; idx += 256){
        int r = idx >> 7, c = idx & 127;
        wls[r][c] = wl[idx];
        wrs[r][c] = wr[idx];
    }
    int wv = t >> 6, lane = t & 63;
    int o = t & 63, nd = t >> 6;
    for (int tile = blockIdx.x; tile < NN/4; tile += gridDim.x){
        int n = tile*4 + wv;
        __syncthreads();
        int r0 = row_ptr[n], deg = row_ptr[n+1] - r0;
        float ax = 0.f, ay = 0.f;
        #pragma unroll 2
        for (int i = 0; i < deg; i++){
            int s = col[r0+i];
            float2 v = *(const float2*)(h1 + (size_t)s*128 + lane*2);
            ax += v.x; ay += v.y;
        }
        float inv = deg > 0 ? 1.f/(float)deg : 0.f;
        mean_s[wv][lane*2]   = ax*inv;
        mean_s[wv][lane*2+1] = ay*inv;
        float2 sv = *(const float2*)(h1 + (size_t)n*128 + lane*2);
        self_s[wv][lane*2]   = sv.x;
        self_s[wv][lane*2+1] = sv.y;
        __syncthreads();
        float oacc = bl[o];
        #pragma unroll 4
        for (int k = 0; k < 128; k++)
            oacc += mean_s[nd][k]*wls[o][k] + self_s[nd][k]*wrs[o][k];
        oacc = eluf(oacc);
        oacc = (oacc - m2[o]) * rsqrtf(v2[o] + 1e-5f) * g2[o] + b2[o];
        h2[(size_t)(tile*4 + nd)*64 + o] = oacc;
    }
}

// ---- GCN linear: hw = h2 @ gcn_w.T [N,32]; LDS-staged W ----
__global__ __launch_bounds__(256) void k_hw(const float* __restrict__ h2,
        const float* __restrict__ w, float* __restrict__ hw){
    __shared__ float ws[32][65];
    __shared__ float hs[32][65];
    int t = threadIdx.x;
    for (int idx = t; idx < 32*64; idx += 256){
        int r = idx >> 6, c = idx & 63;
        ws[r][c] = w[idx];
    }
    int o = t & 31, ndq = t >> 5;
    for (int tile = blockIdx.x; tile < NN/32; tile += gridDim.x){
        int nb = tile*32;
        __syncthreads();
        for (int idx = t; idx < 32*64; idx += 256){
            int r = idx >> 6, c = idx & 63;
            hs[r][c] = h2[(size_t)(nb + r)*64 + c];
        }
        __syncthreads();
        #pragma unroll
        for (int pass = 0; pass < 4; pass++){
            int nd = pass*8 + ndq;
            float acc = 0.f;
            #pragma unroll
            for (int k = 0; k < 64; k++) acc += hs[nd][k]*ws[o][k];
            hw[(size_t)(nb + nd)*32 + o] = acc;
        }
    }
}

__global__ void k_dinv(const int* __restrict__ row_ptr, float* __restrict__ dinv){
    int n = blockIdx.x*blockDim.x + threadIdx.x;
    if (n < NN) dinv[n] = rsqrtf((float)(row_ptr[n+1] - row_ptr[n] + 1));
}

// ---- GCN aggregation + ELU + BN3 -> out [N,32]; 4 nodes/block ----
__global__ __launch_bounds__(256) void k_gcn(const int* __restrict__ row_ptr,
        const int* __restrict__ col, const float* __restrict__ hw,
        const float* __restrict__ dinv, const float* __restrict__ gb,
        const float* __restrict__ g3, const float* __restrict__ b3,
        const float* __restrict__ m3, const float* __restrict__ v3,
        float* __restrict__ out){
    int t = threadIdx.x;
    int n = blockIdx.x*4 + (t >> 6);
    int lane = t & 63, o = lane & 31, half = lane >> 5;
    int r0 = row_ptr[n], deg = row_ptr[n+1] - r0;
    float dn = dinv[n];
    float acc = 0.f;
    for (int i = half; i < deg; i += 2){
        int s = col[r0+i];
        acc += dinv[s] * hw[(size_t)s*32 + o];
    }
    acc += __shfl_xor(acc, 32);
    float tot = acc * dn + dn*dn*hw[(size_t)n*32 + o];
    if (half == 0){
        tot += gb[o];
        tot = eluf(tot);
        tot = (tot - m3[o]) * rsqrtf(v3[o] + 1e-5f) * g3[o] + b3[o];
        out[(size_t)n*32 + o] = tot;
    }
}

extern "C" void kernel_launch(void* const* d_in, const int* in_sizes, int n_in,
                              void* d_out, int out_size, void* d_ws, size_t ws_size,
                              hipStream_t stream)
{
    const float* x     = (const float*)d_in[0];
    const int*   ei    = (const int*)d_in[1];
    const float* gat_w = (const float*)d_in[2];
    const float* att_s = (const float*)d_in[3];
    const float* att_d = (const float*)d_in[4];
    const float* gat_b = (const float*)d_in[5];
    const float* bn1g = (const float*)d_in[6],  *bn1b = (const float*)d_in[7];
    const float* bn1m = (const float*)d_in[8],  *bn1v = (const float*)d_in[9];
    const float* sage_wl = (const float*)d_in[10];
    const float* sage_bl = (const float*)d_in[11];
    const float* sage_wr = (const float*)d_in[12];
    const float* bn2g = (const float*)d_in[13], *bn2b = (const float*)d_in[14];
    const float* bn2m = (const float*)d_in[15], *bn2v = (const float*)d_in[16];
    const float* gcn_w = (const float*)d_in[17];
    const float* gcn_b = (const float*)d_in[18];
    const float* bn3g = (const float*)d_in[19], *bn3b = (const float*)d_in[20];
    const float* bn3m = (const float*)d_in[21], *bn3v = (const float*)d_in[22];

    const int* src  = ei;
    const int* dstp = ei + EE;

    float* f    = (float*)d_ws;
    float* xw   = f;                          // N*128 ; later aliased: h2 (N*64) + hw (N*32)
    float* h1   = f + (size_t)NN*128;         // N*128
    float* a_s  = h1 + (size_t)NN*128;        // N*4
    float* a_d  = a_s + (size_t)NN*4;         // N*4
    float* dinv = a_d + (size_t)NN*4;         // N
    int* row_ptr = (int*)(dinv + NN);         // N+1
    int* counts  = row_ptr + (NN+1);          // N
    int* col     = counts + NN;               // E
    float* h2 = xw;                           // alias (xw dead after k_gat)
    float* hw = xw + (size_t)NN*64;
    float* out = (float*)d_out;

    hipMemsetAsync(counts, 0, NN*sizeof(int), stream);
    k_count<<<(EE+255)/256, 256, 0, stream>>>(dstp, counts);
    k_scan<<<1, 1024, 0, stream>>>(counts, row_ptr);
    hipMemsetAsync(counts, 0, NN*sizeof(int), stream);
    k_scatter<<<(EE+255)/256, 256, 0, stream>>>(src, dstp, row_ptr, counts, col);

    k_xw<<<768, 256, 0, stream>>>(x, gat_w, att_s, att_d, xw, a_s, a_d);
    k_gat<<<NN, 128, 0, stream>>>(row_ptr, col, a_s, a_d, xw, gat_b,
                                  bn1g, bn1b, bn1m, bn1v, h1);
    k_sage<<<1024, 256, 0, stream>>>(row_ptr, col, h1, sage_wl, sage_bl, sage_wr,
                                     bn2g, bn2b, bn2m, bn2v, h2);
    k_hw<<<512, 256, 0, stream>>>(h2, gcn_w, hw);
    k_dinv<<<(NN+255)/256, 256, 0, stream>>>(row_ptr, dinv);
    k_gcn<<<NN/4, 256, 0, stream>>>(row_ptr, col, hw, dinv, gcn_b,
                                    bn3g, bn3b, bn3m, bn3v, out);
}

// Round 5
// 599.268 us; speedup vs baseline: 2.4723x; 1.4010x over previous
//
#include <hip/hip_runtime.h>

#define NN 60000
#define EE 1200000
#define NB1 ((NN+255)/256)

__device__ __forceinline__ float leakyf(float x){ return x >= 0.f ? x : 0.2f*x; }
__device__ __forceinline__ float eluf(float x){ return x > 0.f ? x : expm1f(x); }

// ---- CSR build ----
__global__ void k_count(const int* __restrict__ dst, int* __restrict__ counts){
    int e = blockIdx.x*blockDim.x + threadIdx.x;
    if (e < EE) atomicAdd(&counts[dst[e]], 1);
}

__global__ __launch_bounds__(256) void k_bsum(const int* __restrict__ counts,
                                              int* __restrict__ bsum){
    __shared__ int sh[256];
    int t = threadIdx.x, i = blockIdx.x*256 + t;
    sh[t] = (i < NN) ? counts[i] : 0;
    __syncthreads();
    for (int off = 128; off; off >>= 1){
        if (t < off) sh[t] += sh[t+off];
        __syncthreads();
    }
    if (t == 0) bsum[blockIdx.x] = sh[0];
}

__global__ __launch_bounds__(256) void k_scan2(const int* __restrict__ bsum,
                                               int* __restrict__ ebsum){
    __shared__ int sh[256];
    int t = threadIdx.x;
    int v = (t < NB1) ? bsum[t] : 0;
    sh[t] = v; __syncthreads();
    for (int off = 1; off < 256; off <<= 1){
        int o = (t >= off) ? sh[t-off] : 0;
        __syncthreads();
        sh[t] += o;
        __syncthreads();
    }
    ebsum[t] = sh[t] - v;                 // exclusive
    if (t == 255) ebsum[256] = sh[255];   // total
}

__global__ __launch_bounds__(256) void k_rowptr(const int* __restrict__ counts,
        const int* __restrict__ ebsum, int* __restrict__ row_ptr){
    __shared__ int sh[256];
    int t = threadIdx.x, i = blockIdx.x*256 + t;
    int v = (i < NN) ? counts[i] : 0;
    sh[t] = v; __syncthreads();
    for (int off = 1; off < 256; off <<= 1){
        int o = (t >= off) ? sh[t-off] : 0;
        __syncthreads();
        sh[t] += o;
        __syncthreads();
    }
    if (i < NN) row_ptr[i] = ebsum[blockIdx.x] + sh[t] - v;
    if (blockIdx.x == 0 && t == 0) row_ptr[NN] = ebsum[256];
}

__global__ void k_scatter(const int* __restrict__ src, const int* __restrict__ dst,
                          const int* __restrict__ row_ptr, int* __restrict__ cursor,
                          int* __restrict__ col){
    int e = blockIdx.x*blockDim.x + threadIdx.x;
    if (e < EE){
        int d = dst[e];
        int p = row_ptr[d] + atomicAdd(&cursor[d], 1);
        col[p] = src[e];
    }
}

// ---- GAT linear: xw = x @ gat_w.T [N,128]; a_src/a_dst [N,4]. LDS-staged W ----
#define NTXW 16
__global__ __launch_bounds__(256) void k_xw(const float* __restrict__ x,
        const float* __restrict__ w, const float* __restrict__ att_s,
        const float* __restrict__ att_d, float* __restrict__ xw,
        float* __restrict__ a_src, float* __restrict__ a_dst){
    __shared__ float ws[128][65];
    __shared__ float xs[NTXW][65];
    int t = threadIdx.x;
    for (int idx = t; idx < 128*64; idx += 256){
        int r = idx >> 6, c = idx & 63;
        ws[r][c] = w[idx];
    }
    int o = t & 127;
    float as = att_s[o], ad = att_d[o];
    int h = o >> 5, c = o & 31;
    for (int tile = blockIdx.x; tile < NN/NTXW; tile += gridDim.x){
        int nb = tile * NTXW;
        __syncthreads();
        for (int idx = t; idx < NTXW*64; idx += 256){
            int r = idx >> 6, cc = idx & 63;
            xs[r][cc] = x[(size_t)(nb + r)*64 + cc];
        }
        __syncthreads();
        #pragma unroll
        for (int pass = 0; pass < NTXW/2; ++pass){
            int nd = pass*2 + (t >> 7);
            float acc = 0.f;
            #pragma unroll
            for (int k = 0; k < 64; k++) acc += xs[nd][k]*ws[o][k];
            int n = nb + nd;
            xw[(size_t)n*128 + o] = acc;
            float vs = acc*as, vd = acc*ad;
            #pragma unroll
            for (int d2 = 1; d2 < 32; d2 <<= 1){ vs += __shfl_xor(vs,d2); vd += __shfl_xor(vd,d2); }
            if (c == 0){ a_src[n*4 + h] = vs; a_dst[n*4 + h] = vd; }
        }
    }
}

// ---- GAT aggregation: online softmax + wave-split gather + ELU + BN1 -> h1 ----
__global__ __launch_bounds__(128) void k_gat(const int* __restrict__ rp,
        const int* __restrict__ col, const float* __restrict__ a_src,
        const float* __restrict__ a_dst, const float* __restrict__ xw,
        const float* __restrict__ gb,
        const float* __restrict__ g1, const float* __restrict__ b1,
        const float* __restrict__ m1, const float* __restrict__ v1,
        float* __restrict__ h1){
    int n = blockIdx.x, t = threadIdx.x;
    int lane = t & 63, wv = t >> 6;
    int r0 = rp[n], deg = rp[n+1] - r0;
    __shared__ float red2[2][4][2];
    __shared__ float MXs[4], Sinv_s[4];
    __shared__ float alpha_s[32][4];
    __shared__ int col_s[32];
    __shared__ float redbuf[2][128];

    int ha = t & 3;
    int slot = t >> 2;            // 0..31 across both waves
    float adh_a = a_dst[n*4 + ha];
    float selfl = leakyf(a_src[n*4 + ha] + adh_a);

    // fused online max+expsum (self counted once by t<4)
    float m = selfl;
    float s = (t < 4) ? 1.f : 0.f;
    for (int i = slot; i < deg; i += 32){
        float l = leakyf(a_src[col[r0+i]*4 + ha] + adh_a);
        float mn = fmaxf(m, l);
        s = s*__expf(m - mn) + __expf(l - mn);
        m = mn;
    }
    #pragma unroll
    for (int d = 4; d < 64; d <<= 1){
        float mo = __shfl_xor(m, d), so = __shfl_xor(s, d);
        float mn = fmaxf(m, mo);
        s = s*__expf(m - mn) + so*__expf(mo - mn);
        m = mn;
    }
    if (lane < 4){ red2[wv][lane][0] = m; red2[wv][lane][1] = s; }
    __syncthreads();
    if (t < 4){
        float m0 = red2[0][t][0], s0 = red2[0][t][1];
        float m1v = red2[1][t][0], s1 = red2[1][t][1];
        float mn = fmaxf(m0, m1v);
        float S = s0*__expf(m0-mn) + s1*__expf(m1v-mn) + 1e-16f;
        MXs[t] = mn; Sinv_s[t] = 1.f/S;
    }
    __syncthreads();

    // phase C: chunked alpha + one edge per wave, float2 channels
    int h = lane >> 4;            // head of channels lane*2, lane*2+1
    float2 acc = make_float2(0.f, 0.f);
    if (wv == 0){
        float al_self = __expf(leakyf(a_src[n*4+h] + a_dst[n*4+h]) - MXs[h]) * Sinv_s[h];
        float2 v = *(const float2*)(xw + (size_t)n*128 + lane*2);
        acc.x = v.x*al_self; acc.y = v.y*al_self;
    }
    int e4 = t >> 2;
    for (int base = 0; base < deg; base += 32){
        int cnt = min(32, deg - base);
        __syncthreads();
        if (e4 < cnt){
            int sidx = col[r0 + base + e4];
            if (ha == 0) col_s[e4] = sidx;
            alpha_s[e4][ha] = __expf(leakyf(a_src[sidx*4 + ha] + adh_a) - MXs[ha]) * Sinv_s[ha];
        }
        __syncthreads();
        for (int i = wv; i < cnt; i += 2){
            int sidx = col_s[i];
            float al = alpha_s[i][h];
            float2 v = *(const float2*)(xw + (size_t)sidx*128 + lane*2);
            acc.x += al*v.x; acc.y += al*v.y;
        }
    }
    redbuf[wv][lane*2]   = acc.x;
    redbuf[wv][lane*2+1] = acc.y;
    __syncthreads();
    int o = t;
    float tot = redbuf[0][o] + redbuf[1][o] + gb[o];
    tot = eluf(tot);
    tot = (tot - m1[o]) * rsqrtf(v1[o] + 1e-5f) * g1[o] + b1[o];
    h1[(size_t)n*128 + o] = tot;
}

// ---- SAGE gather-mean: one wave per node, no LDS, max occupancy ----
__global__ __launch_bounds__(256) void k_mean(const int* __restrict__ rp,
        const int* __restrict__ col, const float* __restrict__ h1,
        float* __restrict__ mean){
    int gw = (blockIdx.x*256 + threadIdx.x) >> 6;
    int nwaves = (gridDim.x*256) >> 6;
    int lane = threadIdx.x & 63;
    for (int n = gw; n < NN; n += nwaves){
        int r0 = rp[n], deg = rp[n+1] - r0;
        float ax = 0.f, ay = 0.f;
        #pragma unroll 4
        for (int i = 0; i < deg; i++){
            int s = col[r0+i];
            float2 v = *(const float2*)(h1 + (size_t)s*128 + lane*2);
            ax += v.x; ay += v.y;
        }
        float inv = deg > 0 ? 1.f/(float)deg : 0.f;
        *(float2*)(mean + (size_t)n*128 + lane*2) = make_float2(ax*inv, ay*inv);
    }
}

// ---- SAGE transform (reg-tiled) + ELU + BN2, fused GCN hw GEMM ----
#define SAGE_T 32
__global__ __launch_bounds__(256) void k_sage_mm(
        const float* __restrict__ mean, const float* __restrict__ h1,
        const float* __restrict__ wl, const float* __restrict__ bl,
        const float* __restrict__ wr, const float* __restrict__ gcw,
        const float* __restrict__ g2, const float* __restrict__ b2,
        const float* __restrict__ m2, const float* __restrict__ v2,
        float* __restrict__ hw_out)   // base = h1 + 64 (in-place cols 64..95)
{
    __shared__ float wlT[128][68];
    __shared__ float wrT[128][68];
    __shared__ float gcT[64][36];
    __shared__ float mean_s[SAGE_T][132];
    __shared__ float self_s[SAGE_T][132];
    __shared__ float h2_s[SAGE_T][68];
    int t = threadIdx.x;
    // stage weights transposed [k][o]
    #pragma unroll
    for (int q = 0; q < 8; q++){
        int fi = q*256 + t;
        int o = fi >> 5, k4 = (fi & 31)*4;
        float w4[4];
        *(float4*)w4 = *(const float4*)(wl + o*128 + k4);
        #pragma unroll
        for (int j = 0; j < 4; j++) wlT[k4+j][o] = w4[j];
        *(float4*)w4 = *(const float4*)(wr + o*128 + k4);
        #pragma unroll
        for (int j = 0; j < 4; j++) wrT[k4+j][o] = w4[j];
    }
    #pragma unroll
    for (int q = 0; q < 2; q++){
        int fi = q*256 + t;
        int o = fi >> 4, k4 = (fi & 15)*4;
        float w4[4];
        *(float4*)w4 = *(const float4*)(gcw + o*64 + k4);
        #pragma unroll
        for (int j = 0; j < 4; j++) gcT[k4+j][o] = w4[j];
    }
    int ob = (t & 15)*4;
    int g  = t >> 4;
    int n0l = 2*g, n1l = 2*g + 1;
    float blv[4], sc2[4], sh2[4];
    #pragma unroll
    for (int j = 0; j < 4; j++){
        int o = ob + j;
        blv[j] = bl[o];
        float sc = g2[o] * rsqrtf(v2[o] + 1e-5f);
        sc2[j] = sc;
        sh2[j] = b2[o] - m2[o]*sc;
    }
    for (int nb = blockIdx.x*SAGE_T; nb < NN; nb += gridDim.x*SAGE_T){
        __syncthreads();
        #pragma unroll
        for (int q = 0; q < 4; q++){
            int fi = q*256 + t;
            int j = fi >> 5, kc = (fi & 31)*4;
            *(float4*)&mean_s[j][kc] = *(const float4*)(mean + (size_t)(nb+j)*128 + kc);
            *(float4*)&self_s[j][kc] = *(const float4*)(h1 + (size_t)(nb+j)*128 + kc);
        }
        __syncthreads();
        float a0[4] = {blv[0],blv[1],blv[2],blv[3]};
        float a1[4] = {blv[0],blv[1],blv[2],blv[3]};
        for (int kk = 0; kk < 128; kk += 4){
            float f0[4], f1[4], e0[4], e1[4];
            *(float4*)f0 = *(const float4*)&mean_s[n0l][kk];
            *(float4*)f1 = *(const float4*)&mean_s[n1l][kk];
            *(float4*)e0 = *(const float4*)&self_s[n0l][kk];
            *(float4*)e1 = *(const float4*)&self_s[n1l][kk];
            #pragma unroll
            for (int j2 = 0; j2 < 4; j2++){
                float wl4[4], wr4[4];
                *(float4*)wl4 = *(const float4*)&wlT[kk+j2][ob];
                *(float4*)wr4 = *(const float4*)&wrT[kk+j2][ob];
                #pragma unroll
                for (int j = 0; j < 4; j++){
                    a0[j] += f0[j2]*wl4[j] + e0[j2]*wr4[j];
                    a1[j] += f1[j2]*wl4[j] + e1[j2]*wr4[j];
                }
            }
        }
        #pragma unroll
        for (int j = 0; j < 4; j++){
            h2_s[n0l][ob+j] = eluf(a0[j])*sc2[j] + sh2[j];
            h2_s[n1l][ob+j] = eluf(a1[j])*sc2[j] + sh2[j];
        }
        __syncthreads();
        int n = t >> 3, o4 = (t & 7)*4;
        float c[4] = {0.f,0.f,0.f,0.f};
        for (int k = 0; k < 64; k++){
            float hv = h2_s[n][k];
            float g4[4];
            *(float4*)g4 = *(const float4*)&gcT[k][o4];
            #pragma unroll
            for (int j = 0; j < 4; j++) c[j] += hv * g4[j];
        }
        *(float4*)(hw_out + (size_t)(nb+n)*128 + o4) = make_float4(c[0],c[1],c[2],c[3]);
    }
}

__global__ void k_dinv(const int* __restrict__ row_ptr, float* __restrict__ dinv){
    int n = blockIdx.x*blockDim.x + threadIdx.x;
    if (n < NN) dinv[n] = rsqrtf((float)(row_ptr[n+1] - row_ptr[n] + 1));
}

// ---- GCN aggregation + ELU + BN3 -> out [N,32]; hw rows at stride 128 ----
__global__ __launch_bounds__(256) void k_gcn(const int* __restrict__ row_ptr,
        const int* __restrict__ col, const float* __restrict__ hws,
        const float* __restrict__ dinv, const float* __restrict__ gb,
        const float* __restrict__ g3, const float* __restrict__ b3,
        const float* __restrict__ m3, const float* __restrict__ v3,
        float* __restrict__ out){
    int t = threadIdx.x;
    int n = blockIdx.x*4 + (t >> 6);
    int lane = t & 63, o = lane & 31, half = lane >> 5;
    int r0 = row_ptr[n], deg = row_ptr[n+1] - r0;
    float dn = dinv[n];
    float acc = 0.f;
    for (int i = half; i < deg; i += 2){
        int s = col[r0+i];
        acc += dinv[s] * hws[(size_t)s*128 + o];
    }
    acc += __shfl_xor(acc, 32);
    float tot = acc * dn + dn*dn*hws[(size_t)n*128 + o];
    if (half == 0){
        tot += gb[o];
        tot = eluf(tot);
        tot = (tot - m3[o]) * rsqrtf(v3[o] + 1e-5f) * g3[o] + b3[o];
        out[(size_t)n*32 + o] = tot;
    }
}

extern "C" void kernel_launch(void* const* d_in, const int* in_sizes, int n_in,
                              void* d_out, int out_size, void* d_ws, size_t ws_size,
                              hipStream_t stream)
{
    const float* x     = (const float*)d_in[0];
    const int*   ei    = (const int*)d_in[1];
    const float* gat_w = (const float*)d_in[2];
    const float* att_s = (const float*)d_in[3];
    const float* att_d = (const float*)d_in[4];
    const float* gat_b = (const float*)d_in[5];
    const float* bn1g = (const float*)d_in[6],  *bn1b = (const float*)d_in[7];
    const float* bn1m = (const float*)d_in[8],  *bn1v = (const float*)d_in[9];
    const float* sage_wl = (const float*)d_in[10];
    const float* sage_bl = (const float*)d_in[11];
    const float* sage_wr = (const float*)d_in[12];
    const float* bn2g = (const float*)d_in[13], *bn2b = (const float*)d_in[14];
    const float* bn2m = (const float*)d_in[15], *bn2v = (const float*)d_in[16];
    const float* gcn_w = (const float*)d_in[17];
    const float* gcn_b = (const float*)d_in[18];
    const float* bn3g = (const float*)d_in[19], *bn3b = (const float*)d_in[20];
    const float* bn3m = (const float*)d_in[21], *bn3v = (const float*)d_in[22];

    const int* src  = ei;
    const int* dstp = ei + EE;

    float* f    = (float*)d_ws;
    float* xw   = f;                          // N*128 ; reused as `mean` after k_gat
    float* h1   = f + (size_t)NN*128;         // N*128 ; cols 64..95 become hw
    float* a_s  = h1 + (size_t)NN*128;        // N*4
    float* a_d  = a_s + (size_t)NN*4;         // N*4
    float* dinv = a_d + (size_t)NN*4;         // N
    int* row_ptr = (int*)(dinv + NN);         // N+1
    int* counts  = row_ptr + (NN+1);          // N (also cursor)
    int* col     = counts + NN;               // E
    int* bsum    = col + EE;                  // NB1
    int* ebsum   = bsum + NB1;                // 257
    float* mean  = xw;
    float* hws   = h1 + 64;                   // hw rows, stride 128
    float* out = (float*)d_out;

    hipMemsetAsync(counts, 0, NN*sizeof(int), stream);
    k_count<<<(EE+255)/256, 256, 0, stream>>>(dstp, counts);
    k_bsum<<<NB1, 256, 0, stream>>>(counts, bsum);
    k_scan2<<<1, 256, 0, stream>>>(bsum, ebsum);
    k_rowptr<<<NB1, 256, 0, stream>>>(counts, ebsum, row_ptr);
    hipMemsetAsync(counts, 0, NN*sizeof(int), stream);
    k_scatter<<<(EE+255)/256, 256, 0, stream>>>(src, dstp, row_ptr, counts, col);
    k_dinv<<<(NN+255)/256, 256, 0, stream>>>(row_ptr, dinv);

    k_xw<<<768, 256, 0, stream>>>(x, gat_w, att_s, att_d, xw, a_s, a_d);
    k_gat<<<NN, 128, 0, stream>>>(row_ptr, col, a_s, a_d, xw, gat_b,
                                  bn1g, bn1b, bn1m, bn1v, h1);
    k_mean<<<2048, 256, 0, stream>>>(row_ptr, col, h1, mean);
    k_sage_mm<<<NN/SAGE_T, 256, 0, stream>>>(mean, h1, sage_wl, sage_bl, sage_wr,
                                             gcn_w, bn2g, bn2b, bn2m, bn2v, hws);
    k_gcn<<<NN/4, 256, 0, stream>>>(row_ptr, col, hws, dinv, gcn_b,
                                    bn3g, bn3b, bn3m, bn3v, out);
}

// Round 6
// 551.029 us; speedup vs baseline: 2.6887x; 1.0875x over previous
//
#include <hip/hip_runtime.h>

#define NN 60000
#define EE 1200000
#define NB1 ((NN+255)/256)

__device__ __forceinline__ float leakyf(float x){ return x >= 0.f ? x : 0.2f*x; }
__device__ __forceinline__ float eluf(float x){ return x > 0.f ? x : expm1f(x); }

// bf16 helpers (payload arrays are bf16; all math fp32)
__device__ __forceinline__ float bflo(uint v){ union{uint i;float f;}c; c.i = v<<16; return c.f; }
__device__ __forceinline__ float bfhi(uint v){ union{uint i;float f;}c; c.i = v & 0xffff0000u; return c.f; }
__device__ __forceinline__ ushort f2bf(float f){ union{float f;uint i;}c; c.f=f;
    uint r = c.i + 0x7fffu + ((c.i>>16)&1u); return (ushort)(r>>16); }
__device__ __forceinline__ uint pack2(float a, float b){ return (uint)f2bf(a) | ((uint)f2bf(b)<<16); }

// ---- CSR build ----
__global__ void k_count(const int* __restrict__ dst, int* __restrict__ counts){
    int e = blockIdx.x*blockDim.x + threadIdx.x;
    if (e < EE) atomicAdd(&counts[dst[e]], 1);
}

__global__ __launch_bounds__(256) void k_bsum(const int* __restrict__ counts,
                                              int* __restrict__ bsum){
    __shared__ int sh[256];
    int t = threadIdx.x, i = blockIdx.x*256 + t;
    sh[t] = (i < NN) ? counts[i] : 0;
    __syncthreads();
    for (int off = 128; off; off >>= 1){
        if (t < off) sh[t] += sh[t+off];
        __syncthreads();
    }
    if (t == 0) bsum[blockIdx.x] = sh[0];
}

__global__ __launch_bounds__(256) void k_scan2(const int* __restrict__ bsum,
                                               int* __restrict__ ebsum){
    __shared__ int sh[256];
    int t = threadIdx.x;
    int v = (t < NB1) ? bsum[t] : 0;
    sh[t] = v; __syncthreads();
    for (int off = 1; off < 256; off <<= 1){
        int o = (t >= off) ? sh[t-off] : 0;
        __syncthreads();
        sh[t] += o;
        __syncthreads();
    }
    ebsum[t] = sh[t] - v;
    if (t == 255) ebsum[256] = sh[255];
}

__global__ __launch_bounds__(256) void k_rowptr(const int* __restrict__ counts,
        const int* __restrict__ ebsum, int* __restrict__ row_ptr){
    __shared__ int sh[256];
    int t = threadIdx.x, i = blockIdx.x*256 + t;
    int v = (i < NN) ? counts[i] : 0;
    sh[t] = v; __syncthreads();
    for (int off = 1; off < 256; off <<= 1){
        int o = (t >= off) ? sh[t-off] : 0;
        __syncthreads();
        sh[t] += o;
        __syncthreads();
    }
    if (i < NN) row_ptr[i] = ebsum[blockIdx.x] + sh[t] - v;
    if (blockIdx.x == 0 && t == 0) row_ptr[NN] = ebsum[256];
}

__global__ void k_scatter(const int* __restrict__ src, const int* __restrict__ dst,
                          const int* __restrict__ row_ptr, int* __restrict__ cursor,
                          int* __restrict__ col){
    int e = blockIdx.x*blockDim.x + threadIdx.x;
    if (e < EE){
        int d = dst[e];
        int p = row_ptr[d] + atomicAdd(&cursor[d], 1);
        col[p] = src[e];
    }
}

// ---- weight transpose prep: wlT/wrT [128][64], gcT [64][32] (k-major) ----
__global__ __launch_bounds__(256) void k_wprep(const float* __restrict__ wl,
        const float* __restrict__ wr, const float* __restrict__ gcw,
        float* __restrict__ wlT, float* __restrict__ wrT, float* __restrict__ gcT){
    int t = blockIdx.x*256 + threadIdx.x;
    if (t < 8192){ int o = t >> 7, k = t & 127; wlT[k*64+o] = wl[t]; wrT[k*64+o] = wr[t]; }
    if (t < 2048){ int o = t >> 6, k = t & 63; gcT[k*32+o] = gcw[t]; }
}

// ---- GAT linear: xw(bf16) = x @ gat_w.T; a_src/a_dst [N,4] fp32 ----
#define NTXW 16
__global__ __launch_bounds__(256) void k_xw(const float* __restrict__ x,
        const float* __restrict__ w, const float* __restrict__ att_s,
        const float* __restrict__ att_d, ushort* __restrict__ xw_h,
        float* __restrict__ a_src, float* __restrict__ a_dst){
    __shared__ float ws[128][65];
    __shared__ float xs[NTXW][65];
    int t = threadIdx.x;
    for (int idx = t; idx < 128*64; idx += 256){
        int r = idx >> 6, c = idx & 63;
        ws[r][c] = w[idx];
    }
    int o = t & 127;
    float as = att_s[o], ad = att_d[o];
    int h = o >> 5, c = o & 31;
    for (int tile = blockIdx.x; tile < NN/NTXW; tile += gridDim.x){
        int nb = tile * NTXW;
        __syncthreads();
        for (int idx = t; idx < NTXW*64; idx += 256){
            int r = idx >> 6, cc = idx & 63;
            xs[r][cc] = x[(size_t)(nb + r)*64 + cc];
        }
        __syncthreads();
        #pragma unroll
        for (int pass = 0; pass < NTXW/2; ++pass){
            int nd = pass*2 + (t >> 7);
            float acc = 0.f;
            #pragma unroll
            for (int k = 0; k < 64; k++) acc += xs[nd][k]*ws[o][k];
            int n = nb + nd;
            xw_h[(size_t)n*128 + o] = f2bf(acc);
            float vs = acc*as, vd = acc*ad;
            #pragma unroll
            for (int d2 = 1; d2 < 32; d2 <<= 1){ vs += __shfl_xor(vs,d2); vd += __shfl_xor(vd,d2); }
            if (c == 0){ a_src[n*4 + h] = vs; a_dst[n*4 + h] = vd; }
        }
    }
}

// ---- GAT aggregation: online softmax + uint (2ch bf16) gather -> h1 bf16 ----
__global__ __launch_bounds__(128) void k_gat(const int* __restrict__ rp,
        const int* __restrict__ col, const float* __restrict__ a_src,
        const float* __restrict__ a_dst, const uint* __restrict__ xw_u,
        const float* __restrict__ gb,
        const float* __restrict__ g1, const float* __restrict__ b1,
        const float* __restrict__ m1, const float* __restrict__ v1,
        ushort* __restrict__ h1_h){
    int n = blockIdx.x, t = threadIdx.x;
    int lane = t & 63, wv = t >> 6;
    int r0 = rp[n], deg = rp[n+1] - r0;
    __shared__ float red2[2][4][2];
    __shared__ float MXs[4], Sinv_s[4];
    __shared__ float alpha_s[32][4];
    __shared__ int col_s[32];
    __shared__ float redbuf[2][128];

    int ha = t & 3;
    int slot = t >> 2;
    float adh_a = a_dst[n*4 + ha];
    float selfl = leakyf(a_src[n*4 + ha] + adh_a);

    float m = selfl;
    float s = (t < 4) ? 1.f : 0.f;
    for (int i = slot; i < deg; i += 32){
        float l = leakyf(a_src[col[r0+i]*4 + ha] + adh_a);
        float mn = fmaxf(m, l);
        s = s*__expf(m - mn) + __expf(l - mn);
        m = mn;
    }
    #pragma unroll
    for (int d = 4; d < 64; d <<= 1){
        float mo = __shfl_xor(m, d), so = __shfl_xor(s, d);
        float mn = fmaxf(m, mo);
        s = s*__expf(m - mn) + so*__expf(mo - mn);
        m = mn;
    }
    if (lane < 4){ red2[wv][lane][0] = m; red2[wv][lane][1] = s; }
    __syncthreads();
    if (t < 4){
        float m0 = red2[0][t][0], s0 = red2[0][t][1];
        float m1v = red2[1][t][0], s1 = red2[1][t][1];
        float mn = fmaxf(m0, m1v);
        float S = s0*__expf(m0-mn) + s1*__expf(m1v-mn) + 1e-16f;
        MXs[t] = mn; Sinv_s[t] = 1.f/S;
    }
    __syncthreads();

    // phase C: chunked alpha + uint gather; lane owns channels (2lane, 2lane+1)
    int h = lane >> 4;
    float2 acc = make_float2(0.f, 0.f);
    if (wv == 0){
        float al_self = __expf(leakyf(a_src[n*4+h] + a_dst[n*4+h]) - MXs[h]) * Sinv_s[h];
        uint v = xw_u[(size_t)n*64 + lane];
        acc.x = bflo(v)*al_self; acc.y = bfhi(v)*al_self;
    }
    int e4 = t >> 2;
    for (int base = 0; base < deg; base += 32){
        int cnt = min(32, deg - base);
        __syncthreads();
        if (e4 < cnt){
            int sidx = col[r0 + base + e4];
            if (ha == 0) col_s[e4] = sidx;
            alpha_s[e4][ha] = __expf(leakyf(a_src[sidx*4 + ha] + adh_a) - MXs[ha]) * Sinv_s[ha];
        }
        __syncthreads();
        for (int i = wv; i < cnt; i += 2){
            uint v = xw_u[(size_t)col_s[i]*64 + lane];
            float al = alpha_s[i][h];
            acc.x += al*bflo(v); acc.y += al*bfhi(v);
        }
    }
    redbuf[wv][lane*2]   = acc.x;
    redbuf[wv][lane*2+1] = acc.y;
    __syncthreads();
    int o = t;
    float tot = redbuf[0][o] + redbuf[1][o] + gb[o];
    tot = eluf(tot);
    tot = (tot - m1[o]) * rsqrtf(v1[o] + 1e-5f) * g1[o] + b1[o];
    h1_h[(size_t)n*128 + o] = f2bf(tot);
}

// ---- SAGE gather-mean (bf16 in/out), one wave per node ----
__global__ __launch_bounds__(256) void k_mean(const int* __restrict__ rp,
        const int* __restrict__ col, const uint* __restrict__ h1_u,
        uint* __restrict__ mean_u){
    int gw = (blockIdx.x*256 + threadIdx.x) >> 6;
    int nwaves = (gridDim.x*256) >> 6;
    int lane = threadIdx.x & 63;
    for (int n = gw; n < NN; n += nwaves){
        int r0 = rp[n], deg = rp[n+1] - r0;
        float ax = 0.f, ay = 0.f;
        #pragma unroll 4
        for (int i = 0; i < deg; i++){
            uint v = h1_u[(size_t)col[r0+i]*64 + lane];
            ax += bflo(v); ay += bfhi(v);
        }
        float inv = deg > 0 ? 1.f/(float)deg : 0.f;
        mean_u[(size_t)n*64 + lane] = pack2(ax*inv, ay*inv);
    }
}

// ---- SAGE transform + ELU + BN2 + fused GCN hw GEMM; weights from global ----
#define SAGE_T 32
__global__ __launch_bounds__(256) void k_sage_mm(
        const uint* __restrict__ mean_u, const uint* __restrict__ h1_u,
        const float* __restrict__ wlT, const float* __restrict__ bl,
        const float* __restrict__ wrT, const float* __restrict__ gcT,
        const float* __restrict__ g2, const float* __restrict__ b2,
        const float* __restrict__ m2, const float* __restrict__ v2,
        uint* __restrict__ hw_u)
{
    __shared__ uint mean_s[SAGE_T][68];
    __shared__ uint self_s[SAGE_T][68];
    __shared__ ushort h2_s[SAGE_T][72];
    int t = threadIdx.x;
    int ob = (t & 15)*4, g = t >> 4;
    int n0 = 2*g, n1 = 2*g + 1;
    float blv[4], sc2[4], sh2[4];
    #pragma unroll
    for (int j = 0; j < 4; j++){
        int o = ob + j;
        blv[j] = bl[o];
        float sc = g2[o] * rsqrtf(v2[o] + 1e-5f);
        sc2[j] = sc;
        sh2[j] = b2[o] - m2[o]*sc;
    }
    for (int nb = blockIdx.x*SAGE_T; nb < NN; nb += gridDim.x*SAGE_T){
        __syncthreads();
        #pragma unroll
        for (int q = 0; q < 2; q++){
            int fi = q*256 + t;
            int j = fi >> 4, slot = (fi & 15)*4;
            *(uint4*)&mean_s[j][slot] = *(const uint4*)(mean_u + (size_t)(nb+j)*64 + slot);
            *(uint4*)&self_s[j][slot] = *(const uint4*)(h1_u + (size_t)(nb+j)*64 + slot);
        }
        __syncthreads();
        float a0[4] = {blv[0],blv[1],blv[2],blv[3]};
        float a1[4] = {blv[0],blv[1],blv[2],blv[3]};
        for (int kq = 0; kq < 64; kq++){
            uint mu0 = mean_s[n0][kq], mu1 = mean_s[n1][kq];
            uint su0 = self_s[n0][kq], su1 = self_s[n1][kq];
            float4 wla = *(const float4*)(wlT + (kq*2)*64 + ob);
            float4 wlb = *(const float4*)(wlT + (kq*2+1)*64 + ob);
            float4 wra = *(const float4*)(wrT + (kq*2)*64 + ob);
            float4 wrb = *(const float4*)(wrT + (kq*2+1)*64 + ob);
            float m0a = bflo(mu0), m0b = bfhi(mu0), m1a = bflo(mu1), m1b = bfhi(mu1);
            float s0a = bflo(su0), s0b = bfhi(su0), s1a = bflo(su1), s1b = bfhi(su1);
            a0[0] += m0a*wla.x + m0b*wlb.x + s0a*wra.x + s0b*wrb.x;
            a0[1] += m0a*wla.y + m0b*wlb.y + s0a*wra.y + s0b*wrb.y;
            a0[2] += m0a*wla.z + m0b*wlb.z + s0a*wra.z + s0b*wrb.z;
            a0[3] += m0a*wla.w + m0b*wlb.w + s0a*wra.w + s0b*wrb.w;
            a1[0] += m1a*wla.x + m1b*wlb.x + s1a*wra.x + s1b*wrb.x;
            a1[1] += m1a*wla.y + m1b*wlb.y + s1a*wra.y + s1b*wrb.y;
            a1[2] += m1a*wla.z + m1b*wlb.z + s1a*wra.z + s1b*wrb.z;
            a1[3] += m1a*wla.w + m1b*wlb.w + s1a*wra.w + s1b*wrb.w;
        }
        #pragma unroll
        for (int j = 0; j < 4; j++){
            h2_s[n0][ob+j] = f2bf(eluf(a0[j])*sc2[j] + sh2[j]);
            h2_s[n1][ob+j] = f2bf(eluf(a1[j])*sc2[j] + sh2[j]);
        }
        __syncthreads();
        int n = t >> 3, o4 = (t & 7)*4;
        float c0=0.f, c1=0.f, c2=0.f, c3=0.f;
        for (int k = 0; k < 64; k++){
            float hv = bflo((uint)h2_s[n][k]);
            float4 g4 = *(const float4*)(gcT + k*32 + o4);
            c0 += hv*g4.x; c1 += hv*g4.y; c2 += hv*g4.z; c3 += hv*g4.w;
        }
        hw_u[(size_t)(nb+n)*16 + (o4>>1)]     = pack2(c0, c1);
        hw_u[(size_t)(nb+n)*16 + (o4>>1) + 1] = pack2(c2, c3);
    }
}

__global__ void k_dinv(const int* __restrict__ row_ptr, float* __restrict__ dinv){
    int n = blockIdx.x*blockDim.x + threadIdx.x;
    if (n < NN) dinv[n] = rsqrtf((float)(row_ptr[n+1] - row_ptr[n] + 1));
}

// ---- GCN aggregation + ELU + BN3 -> out [N,32]; hw bf16, 1 wave/node ----
__global__ __launch_bounds__(256) void k_gcn(const int* __restrict__ rp,
        const int* __restrict__ col, const uint* __restrict__ hw_u,
        const float* __restrict__ dinv, const float* __restrict__ gb,
        const float* __restrict__ g3, const float* __restrict__ b3,
        const float* __restrict__ m3, const float* __restrict__ v3,
        float* __restrict__ out){
    int t = threadIdx.x;
    int n = blockIdx.x*4 + (t >> 6);
    int lane = t & 63, u = lane & 15, part = lane >> 4;
    int r0 = rp[n], deg = rp[n+1] - r0;
    float dn = dinv[n];
    float ax = 0.f, ay = 0.f;
    for (int i = part; i < deg; i += 4){
        int s = col[r0+i];
        float dv = dinv[s];
        uint hv = hw_u[(size_t)s*16 + u];
        ax += dv*bflo(hv); ay += dv*bfhi(hv);
    }
    ax += __shfl_xor(ax, 16); ay += __shfl_xor(ay, 16);
    ax += __shfl_xor(ax, 32); ay += __shfl_xor(ay, 32);
    if (part == 0){
        uint sv = hw_u[(size_t)n*16 + u];
        float tx = ax*dn + dn*dn*bflo(sv);
        float ty = ay*dn + dn*dn*bfhi(sv);
        int o0 = 2*u, o1 = o0 + 1;
        tx += gb[o0]; ty += gb[o1];
        tx = eluf(tx); ty = eluf(ty);
        tx = (tx - m3[o0]) * rsqrtf(v3[o0] + 1e-5f) * g3[o0] + b3[o0];
        ty = (ty - m3[o1]) * rsqrtf(v3[o1] + 1e-5f) * g3[o1] + b3[o1];
        *(float2*)(out + (size_t)n*32 + o0) = make_float2(tx, ty);
    }
}

extern "C" void kernel_launch(void* const* d_in, const int* in_sizes, int n_in,
                              void* d_out, int out_size, void* d_ws, size_t ws_size,
                              hipStream_t stream)
{
    const float* x     = (const float*)d_in[0];
    const int*   ei    = (const int*)d_in[1];
    const float* gat_w = (const float*)d_in[2];
    const float* att_s = (const float*)d_in[3];
    const float* att_d = (const float*)d_in[4];
    const float* gat_b = (const float*)d_in[5];
    const float* bn1g = (const float*)d_in[6],  *bn1b = (const float*)d_in[7];
    const float* bn1m = (const float*)d_in[8],  *bn1v = (const float*)d_in[9];
    const float* sage_wl = (const float*)d_in[10];
    const float* sage_bl = (const float*)d_in[11];
    const float* sage_wr = (const float*)d_in[12];
    const float* bn2g = (const float*)d_in[13], *bn2b = (const float*)d_in[14];
    const float* bn2m = (const float*)d_in[15], *bn2v = (const float*)d_in[16];
    const float* gcn_w = (const float*)d_in[17];
    const float* gcn_b = (const float*)d_in[18];
    const float* bn3g = (const float*)d_in[19], *bn3b = (const float*)d_in[20];
    const float* bn3m = (const float*)d_in[21], *bn3v = (const float*)d_in[22];

    const int* src  = ei;
    const int* dstp = ei + EE;

    // workspace layout (bytes)
    char* W = (char*)d_ws;
    ushort* xw_h   = (ushort*)W;                       // N*128 bf16
    ushort* h1_h   = xw_h + (size_t)NN*128;            // N*128 bf16
    ushort* mean_h = h1_h + (size_t)NN*128;            // N*128 bf16
    ushort* hw_h   = mean_h + (size_t)NN*128;          // N*32 bf16
    float* a_s  = (float*)(hw_h + (size_t)NN*32);      // N*4
    float* a_d  = a_s + (size_t)NN*4;                  // N*4
    float* dinv = a_d + (size_t)NN*4;                  // N
    int* row_ptr = (int*)(dinv + NN);                  // N+1
    int* counts  = row_ptr + (NN+1);                   // N (also cursor)
    int* col     = counts + NN;                        // E
    int* bsum    = col + EE;                           // NB1
    int* ebsum   = bsum + NB1;                         // 257
    float* wlT = (float*)(ebsum + 260);                // 8192
    float* wrT = wlT + 8192;                           // 8192
    float* gcT = wrT + 8192;                           // 2048

    const uint* xw_u   = (const uint*)xw_h;
    const uint* h1_u   = (const uint*)h1_h;
    uint* mean_u = (uint*)mean_h;
    uint* hw_u   = (uint*)hw_h;
    float* out = (float*)d_out;

    hipMemsetAsync(counts, 0, NN*sizeof(int), stream);
    k_count<<<(EE+255)/256, 256, 0, stream>>>(dstp, counts);
    k_bsum<<<NB1, 256, 0, stream>>>(counts, bsum);
    k_scan2<<<1, 256, 0, stream>>>(bsum, ebsum);
    k_rowptr<<<NB1, 256, 0, stream>>>(counts, ebsum, row_ptr);
    hipMemsetAsync(counts, 0, NN*sizeof(int), stream);
    k_scatter<<<(EE+255)/256, 256, 0, stream>>>(src, dstp, row_ptr, counts, col);
    k_dinv<<<(NN+255)/256, 256, 0, stream>>>(row_ptr, dinv);
    k_wprep<<<32, 256, 0, stream>>>(sage_wl, sage_wr, gcn_w, wlT, wrT, gcT);

    k_xw<<<768, 256, 0, stream>>>(x, gat_w, att_s, att_d, xw_h, a_s, a_d);
    k_gat<<<NN, 128, 0, stream>>>(row_ptr, col, a_s, a_d, xw_u, gat_b,
                                  bn1g, bn1b, bn1m, bn1v, h1_h);
    k_mean<<<2048, 256, 0, stream>>>(row_ptr, col, h1_u, mean_u);
    k_sage_mm<<<NN/SAGE_T, 256, 0, stream>>>(mean_u, h1_u, wlT, sage_bl, wrT, gcT,
                                             bn2g, bn2b, bn2m, bn2v, hw_u);
    k_gcn<<<NN/4, 256, 0, stream>>>(row_ptr, col, hw_u, dinv, gcn_b,
                                    bn3g, bn3b, bn3m, bn3v, out);
}

// Round 7
// 396.579 us; speedup vs baseline: 3.7359x; 1.3895x over previous
//
#include <hip/hip_runtime.h>

#define NN 60000
#define EE 1200000
#define NB1 ((NN+255)/256)

typedef __attribute__((ext_vector_type(8))) short short8;
typedef __attribute__((ext_vector_type(4))) float f32x4;

__device__ __forceinline__ float leakyf(float x){ return x >= 0.f ? x : 0.2f*x; }
__device__ __forceinline__ float eluf(float x){ return x > 0.f ? x : expm1f(x); }

__device__ __forceinline__ float bflo(uint v){ union{uint i;float f;}c; c.i = v<<16; return c.f; }
__device__ __forceinline__ float bfhi(uint v){ union{uint i;float f;}c; c.i = v & 0xffff0000u; return c.f; }
__device__ __forceinline__ ushort f2bf(float f){ union{float f;uint i;}c; c.f=f;
    uint r = c.i + 0x7fffu + ((c.i>>16)&1u); return (ushort)(r>>16); }
__device__ __forceinline__ uint pack2(float a, float b){ return (uint)f2bf(a) | ((uint)f2bf(b)<<16); }
__device__ __forceinline__ short8 ld8(const uint* p){
    union{ uint4 u; short8 s; } c; c.u = *(const uint4*)p; return c.s; }

// ---- CSR build ----
__global__ void k_count(const int* __restrict__ dst, int* __restrict__ counts){
    int e = blockIdx.x*blockDim.x + threadIdx.x;
    if (e < EE) atomicAdd(&counts[dst[e]], 1);
}

__global__ __launch_bounds__(256) void k_bsum(const int* __restrict__ counts,
                                              int* __restrict__ bsum){
    __shared__ int sh[256];
    int t = threadIdx.x, i = blockIdx.x*256 + t;
    sh[t] = (i < NN) ? counts[i] : 0;
    __syncthreads();
    for (int off = 128; off; off >>= 1){
        if (t < off) sh[t] += sh[t+off];
        __syncthreads();
    }
    if (t == 0) bsum[blockIdx.x] = sh[0];
}

__global__ __launch_bounds__(256) void k_scan2(const int* __restrict__ bsum,
                                               int* __restrict__ ebsum){
    __shared__ int sh[256];
    int t = threadIdx.x;
    int v = (t < NB1) ? bsum[t] : 0;
    sh[t] = v; __syncthreads();
    for (int off = 1; off < 256; off <<= 1){
        int o = (t >= off) ? sh[t-off] : 0;
        __syncthreads();
        sh[t] += o;
        __syncthreads();
    }
    ebsum[t] = sh[t] - v;
    if (t == 255) ebsum[256] = sh[255];
}

__global__ __launch_bounds__(256) void k_rowptr(const int* __restrict__ counts,
        const int* __restrict__ ebsum, int* __restrict__ row_ptr){
    __shared__ int sh[256];
    int t = threadIdx.x, i = blockIdx.x*256 + t;
    int v = (i < NN) ? counts[i] : 0;
    sh[t] = v; __syncthreads();
    for (int off = 1; off < 256; off <<= 1){
        int o = (t >= off) ? sh[t-off] : 0;
        __syncthreads();
        sh[t] += o;
        __syncthreads();
    }
    if (i < NN) row_ptr[i] = ebsum[blockIdx.x] + sh[t] - v;
    if (blockIdx.x == 0 && t == 0) row_ptr[NN] = ebsum[256];
}

__global__ void k_scatter(const int* __restrict__ src, const int* __restrict__ dst,
                          const int* __restrict__ row_ptr, int* __restrict__ cursor,
                          int* __restrict__ col){
    int e = blockIdx.x*blockDim.x + threadIdx.x;
    if (e < EE){
        int d = dst[e];
        int p = row_ptr[d] + atomicAdd(&cursor[d], 1);
        col[p] = src[e];
    }
}

// ---- weight prep: wcat [64][256] bf16 (k<128: wl, k>=128: wr); gcb [32][64] bf16 ----
__global__ __launch_bounds__(256) void k_wprep(const float* __restrict__ wl,
        const float* __restrict__ wr, const float* __restrict__ gcw,
        ushort* __restrict__ wcat, ushort* __restrict__ gcb){
    int t = blockIdx.x*256 + threadIdx.x;
    if (t < 16384){
        int o = t >> 8, k = t & 255;
        float v = (k < 128) ? wl[o*128 + k] : wr[o*128 + (k-128)];
        wcat[t] = f2bf(v);
    }
    if (t < 2048) gcb[t] = f2bf(gcw[t]);
}

// ---- GAT linear: xw(bf16) = x @ gat_w.T; a_src/a_dst [N,4] fp32 ----
#define NTXW 16
__global__ __launch_bounds__(256) void k_xw(const float* __restrict__ x,
        const float* __restrict__ w, const float* __restrict__ att_s,
        const float* __restrict__ att_d, ushort* __restrict__ xw_h,
        float* __restrict__ a_src, float* __restrict__ a_dst){
    __shared__ float ws[128][65];
    __shared__ float xs[NTXW][65];
    int t = threadIdx.x;
    for (int idx = t; idx < 128*64; idx += 256){
        int r = idx >> 6, c = idx & 63;
        ws[r][c] = w[idx];
    }
    int o = t & 127;
    float as = att_s[o], ad = att_d[o];
    int h = o >> 5, c = o & 31;
    for (int tile = blockIdx.x; tile < NN/NTXW; tile += gridDim.x){
        int nb = tile * NTXW;
        __syncthreads();
        for (int idx = t; idx < NTXW*64; idx += 256){
            int r = idx >> 6, cc = idx & 63;
            xs[r][cc] = x[(size_t)(nb + r)*64 + cc];
        }
        __syncthreads();
        #pragma unroll
        for (int pass = 0; pass < NTXW/2; ++pass){
            int nd = pass*2 + (t >> 7);
            float acc = 0.f;
            #pragma unroll
            for (int k = 0; k < 64; k++) acc += xs[nd][k]*ws[o][k];
            int n = nb + nd;
            xw_h[(size_t)n*128 + o] = f2bf(acc);
            float vs = acc*as, vd = acc*ad;
            #pragma unroll
            for (int d2 = 1; d2 < 32; d2 <<= 1){ vs += __shfl_xor(vs,d2); vd += __shfl_xor(vd,d2); }
            if (c == 0){ a_src[n*4 + h] = vs; a_dst[n*4 + h] = vd; }
        }
    }
}

// ---- GAT aggregation: one wave per node, no barriers ----
__global__ __launch_bounds__(256) void k_gat(const int* __restrict__ rp,
        const int* __restrict__ col, const float* __restrict__ a_src,
        const float* __restrict__ a_dst, const uint* __restrict__ xw_u,
        const float* __restrict__ gb,
        const float* __restrict__ g1, const float* __restrict__ b1,
        const float* __restrict__ m1, const float* __restrict__ v1,
        ushort* __restrict__ h1_h){
    int gw = (blockIdx.x*256 + threadIdx.x) >> 6;
    int nwaves = (gridDim.x*256) >> 6;
    int lane = threadIdx.x & 63;
    int h4 = lane & 3;      // head in pass 1 (lane = e4*4 + h4)
    int e4 = lane >> 2;     // edge slot 0..15
    int hh = lane >> 4;     // head in pass 2 (channels 2*lane, 2*lane+1)
    // BN1 constants for this lane's two channels
    int o0 = 2*lane, o1 = o0 + 1;
    float gb0 = gb[o0], gb1 = gb[o1];
    float sc0 = g1[o0]*rsqrtf(v1[o0]+1e-5f), sh0 = b1[o0] - m1[o0]*sc0;
    float sc1 = g1[o1]*rsqrtf(v1[o1]+1e-5f), sh1 = b1[o1] - m1[o1]*sc1;

    for (int n = gw; n < NN; n += nwaves){
        int r0 = rp[n], deg = rp[n+1] - r0;
        float adh4 = a_dst[n*4 + h4];
        float selfl = leakyf(a_src[n*4 + h4] + adh4);
        float m = selfl;
        float s = (lane < 4) ? 1.f : 0.f;
        for (int i = e4; i < deg; i += 16){
            float l = leakyf(a_src[col[r0+i]*4 + h4] + adh4);
            float mn = fmaxf(m, l);
            s = s*__expf(m - mn) + __expf(l - mn);
            m = mn;
        }
        #pragma unroll
        for (int d = 4; d < 64; d <<= 1){
            float mo = __shfl_xor(m, d), so = __shfl_xor(s, d);
            float mn = fmaxf(m, mo);
            s = s*__expf(m - mn) + so*__expf(mo - mn);
            m = mn;
        }
        float MX   = __shfl(m, hh);
        float Sinv = 1.f / (__shfl(s, hh) + 1e-16f);
        float adh  = __shfl(adh4, hh);
        // pass 2: weighted gather (self + edges)
        float ax, ay;
        {
            float al = __expf(leakyf(a_src[n*4 + hh] + adh) - MX) * Sinv;
            uint v = xw_u[(size_t)n*64 + lane];
            ax = bflo(v)*al; ay = bfhi(v)*al;
        }
        #pragma unroll 4
        for (int i = 0; i < deg; i++){
            int sidx = col[r0+i];
            float al = __expf(leakyf(a_src[sidx*4 + hh] + adh) - MX) * Sinv;
            uint v = xw_u[(size_t)sidx*64 + lane];
            ax += al*bflo(v); ay += al*bfhi(v);
        }
        ax += gb0; ay += gb1;
        ax = eluf(ax)*sc0 + sh0;
        ay = eluf(ay)*sc1 + sh1;
        *(uint*)(h1_h + (size_t)n*128 + o0) = pack2(ax, ay);
    }
}

// ---- SAGE gather-mean (bf16 in/out), one wave per node ----
__global__ __launch_bounds__(256) void k_mean(const int* __restrict__ rp,
        const int* __restrict__ col, const uint* __restrict__ h1_u,
        uint* __restrict__ mean_u){
    int gw = (blockIdx.x*256 + threadIdx.x) >> 6;
    int nwaves = (gridDim.x*256) >> 6;
    int lane = threadIdx.x & 63;
    for (int n = gw; n < NN; n += nwaves){
        int r0 = rp[n], deg = rp[n+1] - r0;
        float ax = 0.f, ay = 0.f;
        #pragma unroll 4
        for (int i = 0; i < deg; i++){
            uint v = h1_u[(size_t)col[r0+i]*64 + lane];
            ax += bflo(v); ay += bfhi(v);
        }
        float inv = deg > 0 ? 1.f/(float)deg : 0.f;
        mean_u[(size_t)n*64 + lane] = pack2(ax*inv, ay*inv);
    }
}

// ---- SAGE + BN2 + GCN-hw via MFMA. Tile = 64 nodes, 4 waves. ----
// Wave w owns out-cols [w*16, w*16+16). h2 = [mean|h1] @ wcat.T (K=256).
// Stage 2: hw = h2 @ gcb.T (K=64, 32 outs, 2 col-tiles per wave's 16 rows).
#define STILE 938   // ceil(60000/64)
__global__ __launch_bounds__(256) void k_sage_mfma(
        const uint* __restrict__ mean_u, const uint* __restrict__ h1_u,
        const uint* __restrict__ wcat_u, const float* __restrict__ bl,
        const uint* __restrict__ gcb_u,
        const float* __restrict__ g2, const float* __restrict__ b2,
        const float* __restrict__ m2, const float* __restrict__ v2,
        ushort* __restrict__ hw_h)
{
    __shared__ ushort h2_s[64][72];
    int t = threadIdx.x;
    int w = t >> 6, lane = t & 63;
    int l15 = lane & 15, g = lane >> 4;
    int olane = w*16 + l15;                  // stage-1 out col

    // loop-invariant B-fragments: SAGE weights (8 ksteps) + GCN weights (2 ct x 2 ks)
    short8 bw[8];
    #pragma unroll
    for (int ks = 0; ks < 8; ks++)
        bw[ks] = ld8(wcat_u + (size_t)olane*128 + ks*16 + g*4);
    short8 bg[2][2];
    #pragma unroll
    for (int ct = 0; ct < 2; ct++)
        #pragma unroll
        for (int ks = 0; ks < 2; ks++)
            bg[ct][ks] = ld8(gcb_u + (size_t)(ct*16 + l15)*32 + ks*16 + g*4);

    float blv = bl[olane];
    float scv = g2[olane]*rsqrtf(v2[olane]+1e-5f);
    float shv = b2[olane] - m2[olane]*scv;

    for (int tile = blockIdx.x; tile < STILE; tile += gridDim.x){
        int nb = tile*64;
        __syncthreads();   // protect h2_s from previous iteration's readers
        #pragma unroll
        for (int rt = 0; rt < 4; rt++){
            f32x4 acc = {0.f, 0.f, 0.f, 0.f};
            size_t node = (size_t)(nb + rt*16 + l15);
            const uint* am = mean_u + node*64 + g*4;
            const uint* as = h1_u  + node*64 + g*4;
            #pragma unroll
            for (int ks = 0; ks < 4; ks++)
                acc = __builtin_amdgcn_mfma_f32_16x16x32_bf16(ld8(am + ks*16), bw[ks], acc, 0, 0, 0);
            #pragma unroll
            for (int ks = 0; ks < 4; ks++)
                acc = __builtin_amdgcn_mfma_f32_16x16x32_bf16(ld8(as + ks*16), bw[4+ks], acc, 0, 0, 0);
            #pragma unroll
            for (int r = 0; r < 4; r++){
                int row = rt*16 + g*4 + r;
                h2_s[row][olane] = f2bf(eluf(acc[r] + blv)*scv + shv);
            }
        }
        __syncthreads();
        // stage 2: wave w handles rows [w*16, w*16+16), outs 0..31
        short8 a2[2];
        #pragma unroll
        for (int ks = 0; ks < 2; ks++)
            a2[ks] = *(const short8*)&h2_s[w*16 + l15][ks*32 + g*8];
        #pragma unroll
        for (int ct = 0; ct < 2; ct++){
            f32x4 acc2 = {0.f, 0.f, 0.f, 0.f};
            #pragma unroll
            for (int ks = 0; ks < 2; ks++)
                acc2 = __builtin_amdgcn_mfma_f32_16x16x32_bf16(a2[ks], bg[ct][ks], acc2, 0, 0, 0);
            #pragma unroll
            for (int r = 0; r < 4; r++){
                int row = nb + w*16 + g*4 + r;
                if (row < NN) hw_h[(size_t)row*32 + ct*16 + l15] = f2bf(acc2[r]);
            }
        }
    }
}

__global__ void k_dinv(const int* __restrict__ row_ptr, float* __restrict__ dinv){
    int n = blockIdx.x*blockDim.x + threadIdx.x;
    if (n < NN) dinv[n] = rsqrtf((float)(row_ptr[n+1] - row_ptr[n] + 1));
}

// ---- GCN aggregation + ELU + BN3 -> out [N,32]; hw bf16, 1 wave/node ----
__global__ __launch_bounds__(256) void k_gcn(const int* __restrict__ rp,
        const int* __restrict__ col, const uint* __restrict__ hw_u,
        const float* __restrict__ dinv, const float* __restrict__ gb,
        const float* __restrict__ g3, const float* __restrict__ b3,
        const float* __restrict__ m3, const float* __restrict__ v3,
        float* __restrict__ out){
    int t = threadIdx.x;
    int n = blockIdx.x*4 + (t >> 6);
    int lane = t & 63, u = lane & 15, part = lane >> 4;
    int r0 = rp[n], deg = rp[n+1] - r0;
    float dn = dinv[n];
    float ax = 0.f, ay = 0.f;
    for (int i = part; i < deg; i += 4){
        int s = col[r0+i];
        float dv = dinv[s];
        uint hv = hw_u[(size_t)s*16 + u];
        ax += dv*bflo(hv); ay += dv*bfhi(hv);
    }
    ax += __shfl_xor(ax, 16); ay += __shfl_xor(ay, 16);
    ax += __shfl_xor(ax, 32); ay += __shfl_xor(ay, 32);
    if (part == 0){
        uint sv = hw_u[(size_t)n*16 + u];
        float tx = ax*dn + dn*dn*bflo(sv);
        float ty = ay*dn + dn*dn*bfhi(sv);
        int o0 = 2*u, o1 = o0 + 1;
        tx += gb[o0]; ty += gb[o1];
        tx = eluf(tx); ty = eluf(ty);
        tx = (tx - m3[o0]) * rsqrtf(v3[o0] + 1e-5f) * g3[o0] + b3[o0];
        ty = (ty - m3[o1]) * rsqrtf(v3[o1] + 1e-5f) * g3[o1] + b3[o1];
        *(float2*)(out + (size_t)n*32 + o0) = make_float2(tx, ty);
    }
}

extern "C" void kernel_launch(void* const* d_in, const int* in_sizes, int n_in,
                              void* d_out, int out_size, void* d_ws, size_t ws_size,
                              hipStream_t stream)
{
    const float* x     = (const float*)d_in[0];
    const int*   ei    = (const int*)d_in[1];
    const float* gat_w = (const float*)d_in[2];
    const float* att_s = (const float*)d_in[3];
    const float* att_d = (const float*)d_in[4];
    const float* gat_b = (const float*)d_in[5];
    const float* bn1g = (const float*)d_in[6],  *bn1b = (const float*)d_in[7];
    const float* bn1m = (const float*)d_in[8],  *bn1v = (const float*)d_in[9];
    const float* sage_wl = (const float*)d_in[10];
    const float* sage_bl = (const float*)d_in[11];
    const float* sage_wr = (const float*)d_in[12];
    const float* bn2g = (const float*)d_in[13], *bn2b = (const float*)d_in[14];
    const float* bn2m = (const float*)d_in[15], *bn2v = (const float*)d_in[16];
    const float* gcn_w = (const float*)d_in[17];
    const float* gcn_b = (const float*)d_in[18];
    const float* bn3g = (const float*)d_in[19], *bn3b = (const float*)d_in[20];
    const float* bn3m = (const float*)d_in[21], *bn3v = (const float*)d_in[22];

    const int* src  = ei;
    const int* dstp = ei + EE;

    char* W = (char*)d_ws;
    ushort* xw_h   = (ushort*)W;                       // N*128 bf16
    ushort* h1_h   = xw_h + (size_t)NN*128;            // N*128 bf16
    ushort* mean_h = h1_h + (size_t)NN*128;            // N*128 bf16
    ushort* hw_h   = mean_h + (size_t)NN*128;          // N*32 bf16
    float* a_s  = (float*)(hw_h + (size_t)NN*32 + 8192); // slack for OOB tile reads
    float* a_d  = a_s + (size_t)NN*4;
    float* dinv = a_d + (size_t)NN*4;
    int* row_ptr = (int*)(dinv + NN);                  // N+1
    int* counts  = row_ptr + (NN+1);                   // N (also cursor)
    int* col     = counts + NN;                        // E
    int* bsum    = col + EE;                           // NB1
    int* ebsum   = bsum + NB1;                         // 257
    ushort* wcat_h = (ushort*)(ebsum + 260);           // 64*256 bf16
    ushort* gcb_h  = wcat_h + 16384;                   // 32*64 bf16

    const uint* xw_u   = (const uint*)xw_h;
    const uint* h1_u   = (const uint*)h1_h;
    uint* mean_u = (uint*)mean_h;
    uint* hw_u   = (uint*)hw_h;
    const uint* wcat_u = (const uint*)wcat_h;
    const uint* gcb_u  = (const uint*)gcb_h;
    float* out = (float*)d_out;

    hipMemsetAsync(counts, 0, NN*sizeof(int), stream);
    k_count<<<(EE+255)/256, 256, 0, stream>>>(dstp, counts);
    k_bsum<<<NB1, 256, 0, stream>>>(counts, bsum);
    k_scan2<<<1, 256, 0, stream>>>(bsum, ebsum);
    k_rowptr<<<NB1, 256, 0, stream>>>(counts, ebsum, row_ptr);
    hipMemsetAsync(counts, 0, NN*sizeof(int), stream);
    k_scatter<<<(EE+255)/256, 256, 0, stream>>>(src, dstp, row_ptr, counts, col);
    k_dinv<<<(NN+255)/256, 256, 0, stream>>>(row_ptr, dinv);
    k_wprep<<<64, 256, 0, stream>>>(sage_wl, sage_wr, gcn_w, wcat_h, gcb_h);

    k_xw<<<768, 256, 0, stream>>>(x, gat_w, att_s, att_d, xw_h, a_s, a_d);
    k_gat<<<2048, 256, 0, stream>>>(row_ptr, col, a_s, a_d, xw_u, gat_b,
                                    bn1g, bn1b, bn1m, bn1v, h1_h);
    k_mean<<<2048, 256, 0, stream>>>(row_ptr, col, h1_u, mean_u);
    k_sage_mfma<<<STILE, 256, 0, stream>>>(mean_u, h1_u, wcat_u, sage_bl, gcb_u,
                                           bn2g, bn2b, bn2m, bn2v, hw_h);
    k_gcn<<<NN/4, 256, 0, stream>>>(row_ptr, col, hw_u, dinv, gcn_b,
                                    bn3g, bn3b, bn3m, bn3v, out);
}

// Round 8
// 336.013 us; speedup vs baseline: 4.4093x; 1.1802x over previous
//
#include <hip/hip_runtime.h>

#define NN 60000
#define EE 1200000
#define NB1 ((NN+255)/256)

typedef __attribute__((ext_vector_type(8))) short short8;
typedef __attribute__((ext_vector_type(4))) float f32x4;

__device__ __forceinline__ float leakyf(float x){ return x >= 0.f ? x : 0.2f*x; }
__device__ __forceinline__ float eluf(float x){ return x > 0.f ? x : expm1f(x); }

__device__ __forceinline__ float bflo(uint v){ union{uint i;float f;}c; c.i = v<<16; return c.f; }
__device__ __forceinline__ float bfhi(uint v){ union{uint i;float f;}c; c.i = v & 0xffff0000u; return c.f; }
__device__ __forceinline__ ushort f2bf(float f){ union{float f;uint i;}c; c.f=f;
    uint r = c.i + 0x7fffu + ((c.i>>16)&1u); return (ushort)(r>>16); }
__device__ __forceinline__ uint pack2(float a, float b){ return (uint)f2bf(a) | ((uint)f2bf(b)<<16); }
__device__ __forceinline__ short8 ld8(const uint* p){
    union{ uint4 u; short8 s; } c; c.u = *(const uint4*)p; return c.s; }

// ---- CSR build ----
__global__ void k_count(const int* __restrict__ dst, int* __restrict__ counts){
    int e = blockIdx.x*blockDim.x + threadIdx.x;
    if (e < EE) atomicAdd(&counts[dst[e]], 1);
}

__global__ __launch_bounds__(256) void k_bsum(const int* __restrict__ counts,
                                              int* __restrict__ bsum){
    __shared__ int sh[256];
    int t = threadIdx.x, i = blockIdx.x*256 + t;
    sh[t] = (i < NN) ? counts[i] : 0;
    __syncthreads();
    for (int off = 128; off; off >>= 1){
        if (t < off) sh[t] += sh[t+off];
        __syncthreads();
    }
    if (t == 0) bsum[blockIdx.x] = sh[0];
}

__global__ __launch_bounds__(256) void k_scan2(const int* __restrict__ bsum,
                                               int* __restrict__ ebsum){
    __shared__ int sh[256];
    int t = threadIdx.x;
    int v = (t < NB1) ? bsum[t] : 0;
    sh[t] = v; __syncthreads();
    for (int off = 1; off < 256; off <<= 1){
        int o = (t >= off) ? sh[t-off] : 0;
        __syncthreads();
        sh[t] += o;
        __syncthreads();
    }
    ebsum[t] = sh[t] - v;
    if (t == 255) ebsum[256] = sh[255];
}

__global__ __launch_bounds__(256) void k_rowptr(const int* __restrict__ counts,
        const int* __restrict__ ebsum, int* __restrict__ row_ptr){
    __shared__ int sh[256];
    int t = threadIdx.x, i = blockIdx.x*256 + t;
    int v = (i < NN) ? counts[i] : 0;
    sh[t] = v; __syncthreads();
    for (int off = 1; off < 256; off <<= 1){
        int o = (t >= off) ? sh[t-off] : 0;
        __syncthreads();
        sh[t] += o;
        __syncthreads();
    }
    if (i < NN) row_ptr[i] = ebsum[blockIdx.x] + sh[t] - v;
    if (blockIdx.x == 0 && t == 0) row_ptr[NN] = ebsum[256];
}

__global__ void k_scatter(const int* __restrict__ src, const int* __restrict__ dst,
                          const int* __restrict__ row_ptr, int* __restrict__ cursor,
                          int* __restrict__ col){
    int e = blockIdx.x*blockDim.x + threadIdx.x;
    if (e < EE){
        int d = dst[e];
        int p = row_ptr[d] + atomicAdd(&cursor[d], 1);
        col[p] = src[e];
    }
}

// ---- weight prep: wcat [64][256] bf16 (k<128: wl, k>=128: wr); gcb [32][64] bf16 ----
__global__ __launch_bounds__(256) void k_wprep(const float* __restrict__ wl,
        const float* __restrict__ wr, const float* __restrict__ gcw,
        ushort* __restrict__ wcat, ushort* __restrict__ gcb){
    int t = blockIdx.x*256 + threadIdx.x;
    if (t < 16384){
        int o = t >> 8, k = t & 255;
        float v = (k < 128) ? wl[o*128 + k] : wr[o*128 + (k-128)];
        wcat[t] = f2bf(v);
    }
    if (t < 2048) gcb[t] = f2bf(gcw[t]);
}

// ---- GAT linear via MFMA: xw(bf16) = x @ gat_w.T; a_src/a_dst [N,4] fp32 ----
// 64-node tile, 4 waves; wave w owns head w (out cols [w*32, w*32+32)).
#define XTILE 938   // ceil(60000/64)
__global__ __launch_bounds__(256) void k_xw_mfma(const float* __restrict__ x,
        const float* __restrict__ w, const float* __restrict__ att_s,
        const float* __restrict__ att_d, ushort* __restrict__ xw_h,
        float* __restrict__ a_src, float* __restrict__ a_dst){
    int t = threadIdx.x;
    int wv = t >> 6, lane = t & 63;
    int l15 = lane & 15, g = lane >> 4;
    // loop-invariant B-frags: col = wv*32 + ct*16 + l15, k = ks*32 + g*8 ..+8
    short8 bw[2][2];
    float attv_s[2], attv_d[2];
    #pragma unroll
    for (int ct = 0; ct < 2; ct++){
        int colo = wv*32 + ct*16 + l15;
        attv_s[ct] = att_s[colo];
        attv_d[ct] = att_d[colo];
        #pragma unroll
        for (int ks = 0; ks < 2; ks++){
            const float* wp = w + colo*64 + ks*32 + g*8;
            short8 b;
            #pragma unroll
            for (int j = 0; j < 8; j++) b[j] = (short)f2bf(wp[j]);
            bw[ct][ks] = b;
        }
    }
    for (int tile = blockIdx.x; tile < XTILE; tile += gridDim.x){
        int nb = tile*64;
        #pragma unroll
        for (int rt = 0; rt < 4; rt++){
            int na = nb + rt*16 + l15;
            const float* xp = x + (size_t)min(na, NN-1)*64;
            short8 a[2];
            #pragma unroll
            for (int ks = 0; ks < 2; ks++){
                float xv[8];
                *(float4*)&xv[0] = *(const float4*)(xp + ks*32 + g*8);
                *(float4*)&xv[4] = *(const float4*)(xp + ks*32 + g*8 + 4);
                short8 av;
                #pragma unroll
                for (int j = 0; j < 8; j++) av[j] = (short)f2bf(xv[j]);
                a[ks] = av;
            }
            f32x4 acc0 = {0.f,0.f,0.f,0.f}, acc1 = {0.f,0.f,0.f,0.f};
            acc0 = __builtin_amdgcn_mfma_f32_16x16x32_bf16(a[0], bw[0][0], acc0, 0, 0, 0);
            acc0 = __builtin_amdgcn_mfma_f32_16x16x32_bf16(a[1], bw[0][1], acc0, 0, 0, 0);
            acc1 = __builtin_amdgcn_mfma_f32_16x16x32_bf16(a[0], bw[1][0], acc1, 0, 0, 0);
            acc1 = __builtin_amdgcn_mfma_f32_16x16x32_bf16(a[1], bw[1][1], acc1, 0, 0, 0);
            // write xw (D: row = g*4+r, col = l15 within col-tile)
            #pragma unroll
            for (int r = 0; r < 4; r++){
                int node = nb + rt*16 + g*4 + r;
                if (node < NN){
                    xw_h[(size_t)node*128 + wv*32 + l15]      = f2bf(acc0[r]);
                    xw_h[(size_t)node*128 + wv*32 + 16 + l15] = f2bf(acc1[r]);
                }
            }
            // attention dots: reduce over the 32 cols of head wv (l15 lanes x 2 ct)
            float ps[4], pd[4];
            #pragma unroll
            for (int r = 0; r < 4; r++){
                ps[r] = acc0[r]*attv_s[0] + acc1[r]*attv_s[1];
                pd[r] = acc0[r]*attv_d[0] + acc1[r]*attv_d[1];
            }
            #pragma unroll
            for (int d = 1; d < 16; d <<= 1){
                #pragma unroll
                for (int r = 0; r < 4; r++){
                    ps[r] += __shfl_xor(ps[r], d);
                    pd[r] += __shfl_xor(pd[r], d);
                }
            }
            if (l15 == 0){
                #pragma unroll
                for (int r = 0; r < 4; r++){
                    int node = nb + rt*16 + g*4 + r;
                    if (node < NN){
                        a_src[node*4 + wv] = ps[r];
                        a_dst[node*4 + wv] = pd[r];
                    }
                }
            }
        }
    }
}

// ---- GAT aggregation: one wave per node, no barriers ----
__global__ __launch_bounds__(256) void k_gat(const int* __restrict__ rp,
        const int* __restrict__ col, const float* __restrict__ a_src,
        const float* __restrict__ a_dst, const uint* __restrict__ xw_u,
        const float* __restrict__ gb,
        const float* __restrict__ g1, const float* __restrict__ b1,
        const float* __restrict__ m1, const float* __restrict__ v1,
        ushort* __restrict__ h1_h){
    int gw = (blockIdx.x*256 + threadIdx.x) >> 6;
    int nwaves = (gridDim.x*256) >> 6;
    int lane = threadIdx.x & 63;
    int h4 = lane & 3;      // head in pass 1 (lane = e4*4 + h4)
    int e4 = lane >> 2;     // edge slot 0..15
    int hh = lane >> 4;     // head in pass 2 (channels 2*lane, 2*lane+1)
    int o0 = 2*lane, o1 = o0 + 1;
    float gb0 = gb[o0], gb1 = gb[o1];
    float sc0 = g1[o0]*rsqrtf(v1[o0]+1e-5f), sh0 = b1[o0] - m1[o0]*sc0;
    float sc1 = g1[o1]*rsqrtf(v1[o1]+1e-5f), sh1 = b1[o1] - m1[o1]*sc1;

    for (int n = gw; n < NN; n += nwaves){
        int r0 = rp[n], deg = rp[n+1] - r0;
        float adh4 = a_dst[n*4 + h4];
        float selfl = leakyf(a_src[n*4 + h4] + adh4);
        float m = selfl;
        float s = (lane < 4) ? 1.f : 0.f;
        for (int i = e4; i < deg; i += 16){
            float l = leakyf(a_src[col[r0+i]*4 + h4] + adh4);
            float mn = fmaxf(m, l);
            s = s*__expf(m - mn) + __expf(l - mn);
            m = mn;
        }
        #pragma unroll
        for (int d = 4; d < 64; d <<= 1){
            float mo = __shfl_xor(m, d), so = __shfl_xor(s, d);
            float mn = fmaxf(m, mo);
            s = s*__expf(m - mn) + so*__expf(mo - mn);
            m = mn;
        }
        float MX   = __shfl(m, hh);
        float Sinv = 1.f / (__shfl(s, hh) + 1e-16f);
        float adh  = __shfl(adh4, hh);
        float ax, ay;
        {
            float al = __expf(leakyf(a_src[n*4 + hh] + adh) - MX) * Sinv;
            uint v = xw_u[(size_t)n*64 + lane];
            ax = bflo(v)*al; ay = bfhi(v)*al;
        }
        #pragma unroll 4
        for (int i = 0; i < deg; i++){
            int sidx = col[r0+i];
            float al = __expf(leakyf(a_src[sidx*4 + hh] + adh) - MX) * Sinv;
            uint v = xw_u[(size_t)sidx*64 + lane];
            ax += al*bflo(v); ay += al*bfhi(v);
        }
        ax += gb0; ay += gb1;
        ax = eluf(ax)*sc0 + sh0;
        ay = eluf(ay)*sc1 + sh1;
        *(uint*)(h1_h + (size_t)n*128 + o0) = pack2(ax, ay);
    }
}

// ---- SAGE gather-mean (bf16 in/out), one wave per node ----
__global__ __launch_bounds__(256) void k_mean(const int* __restrict__ rp,
        const int* __restrict__ col, const uint* __restrict__ h1_u,
        uint* __restrict__ mean_u){
    int gw = (blockIdx.x*256 + threadIdx.x) >> 6;
    int nwaves = (gridDim.x*256) >> 6;
    int lane = threadIdx.x & 63;
    for (int n = gw; n < NN; n += nwaves){
        int r0 = rp[n], deg = rp[n+1] - r0;
        float ax = 0.f, ay = 0.f;
        #pragma unroll 4
        for (int i = 0; i < deg; i++){
            uint v = h1_u[(size_t)col[r0+i]*64 + lane];
            ax += bflo(v); ay += bfhi(v);
        }
        float inv = deg > 0 ? 1.f/(float)deg : 0.f;
        mean_u[(size_t)n*64 + lane] = pack2(ax*inv, ay*inv);
    }
}

// ---- SAGE + BN2 + GCN-hw via MFMA. Tile = 64 nodes, 4 waves. ----
#define STILE 938   // ceil(60000/64)
__global__ __launch_bounds__(256) void k_sage_mfma(
        const uint* __restrict__ mean_u, const uint* __restrict__ h1_u,
        const uint* __restrict__ wcat_u, const float* __restrict__ bl,
        const uint* __restrict__ gcb_u,
        const float* __restrict__ g2, const float* __restrict__ b2,
        const float* __restrict__ m2, const float* __restrict__ v2,
        ushort* __restrict__ hw_h)
{
    __shared__ ushort h2_s[64][72];
    int t = threadIdx.x;
    int w = t >> 6, lane = t & 63;
    int l15 = lane & 15, g = lane >> 4;
    int olane = w*16 + l15;

    short8 bw[8];
    #pragma unroll
    for (int ks = 0; ks < 8; ks++)
        bw[ks] = ld8(wcat_u + (size_t)olane*128 + ks*16 + g*4);
    short8 bg[2][2];
    #pragma unroll
    for (int ct = 0; ct < 2; ct++)
        #pragma unroll
        for (int ks = 0; ks < 2; ks++)
            bg[ct][ks] = ld8(gcb_u + (size_t)(ct*16 + l15)*32 + ks*16 + g*4);

    float blv = bl[olane];
    float scv = g2[olane]*rsqrtf(v2[olane]+1e-5f);
    float shv = b2[olane] - m2[olane]*scv;

    for (int tile = blockIdx.x; tile < STILE; tile += gridDim.x){
        int nb = tile*64;
        __syncthreads();
        #pragma unroll
        for (int rt = 0; rt < 4; rt++){
            f32x4 acc = {0.f, 0.f, 0.f, 0.f};
            size_t node = (size_t)(nb + rt*16 + l15);
            const uint* am = mean_u + node*64 + g*4;
            const uint* as = h1_u  + node*64 + g*4;
            #pragma unroll
            for (int ks = 0; ks < 4; ks++)
                acc = __builtin_amdgcn_mfma_f32_16x16x32_bf16(ld8(am + ks*16), bw[ks], acc, 0, 0, 0);
            #pragma unroll
            for (int ks = 0; ks < 4; ks++)
                acc = __builtin_amdgcn_mfma_f32_16x16x32_bf16(ld8(as + ks*16), bw[4+ks], acc, 0, 0, 0);
            #pragma unroll
            for (int r = 0; r < 4; r++){
                int row = rt*16 + g*4 + r;
                h2_s[row][olane] = f2bf(eluf(acc[r] + blv)*scv + shv);
            }
        }
        __syncthreads();
        short8 a2[2];
        #pragma unroll
        for (int ks = 0; ks < 2; ks++)
            a2[ks] = *(const short8*)&h2_s[w*16 + l15][ks*32 + g*8];
        #pragma unroll
        for (int ct = 0; ct < 2; ct++){
            f32x4 acc2 = {0.f, 0.f, 0.f, 0.f};
            #pragma unroll
            for (int ks = 0; ks < 2; ks++)
                acc2 = __builtin_amdgcn_mfma_f32_16x16x32_bf16(a2[ks], bg[ct][ks], acc2, 0, 0, 0);
            #pragma unroll
            for (int r = 0; r < 4; r++){
                int row = nb + w*16 + g*4 + r;
                if (row < NN) hw_h[(size_t)row*32 + ct*16 + l15] = f2bf(acc2[r]);
            }
        }
    }
}

__global__ void k_dinv(const int* __restrict__ row_ptr, float* __restrict__ dinv){
    int n = blockIdx.x*blockDim.x + threadIdx.x;
    if (n < NN) dinv[n] = rsqrtf((float)(row_ptr[n+1] - row_ptr[n] + 1));
}

// ---- GCN aggregation + ELU + BN3 -> out [N,32]; hw bf16, 1 wave/node ----
__global__ __launch_bounds__(256) void k_gcn(const int* __restrict__ rp,
        const int* __restrict__ col, const uint* __restrict__ hw_u,
        const float* __restrict__ dinv, const float* __restrict__ gb,
        const float* __restrict__ g3, const float* __restrict__ b3,
        const float* __restrict__ m3, const float* __restrict__ v3,
        float* __restrict__ out){
    int t = threadIdx.x;
    int n = blockIdx.x*4 + (t >> 6);
    int lane = t & 63, u = lane & 15, part = lane >> 4;
    int r0 = rp[n], deg = rp[n+1] - r0;
    float dn = dinv[n];
    float ax = 0.f, ay = 0.f;
    for (int i = part; i < deg; i += 4){
        int s = col[r0+i];
        float dv = dinv[s];
        uint hv = hw_u[(size_t)s*16 + u];
        ax += dv*bflo(hv); ay += dv*bfhi(hv);
    }
    ax += __shfl_xor(ax, 16); ay += __shfl_xor(ay, 16);
    ax += __shfl_xor(ax, 32); ay += __shfl_xor(ay, 32);
    if (part == 0){
        uint sv = hw_u[(size_t)n*16 + u];
        float tx = ax*dn + dn*dn*bflo(sv);
        float ty = ay*dn + dn*dn*bfhi(sv);
        int o0 = 2*u, o1 = o0 + 1;
        tx += gb[o0]; ty += gb[o1];
        tx = eluf(tx); ty = eluf(ty);
        tx = (tx - m3[o0]) * rsqrtf(v3[o0] + 1e-5f) * g3[o0] + b3[o0];
        ty = (ty - m3[o1]) * rsqrtf(v3[o1] + 1e-5f) * g3[o1] + b3[o1];
        *(float2*)(out + (size_t)n*32 + o0) = make_float2(tx, ty);
    }
}

extern "C" void kernel_launch(void* const* d_in, const int* in_sizes, int n_in,
                              void* d_out, int out_size, void* d_ws, size_t ws_size,
                              hipStream_t stream)
{
    const float* x     = (const float*)d_in[0];
    const int*   ei    = (const int*)d_in[1];
    const float* gat_w = (const float*)d_in[2];
    const float* att_s = (const float*)d_in[3];
    const float* att_d = (const float*)d_in[4];
    const float* gat_b = (const float*)d_in[5];
    const float* bn1g = (const float*)d_in[6],  *bn1b = (const float*)d_in[7];
    const float* bn1m = (const float*)d_in[8],  *bn1v = (const float*)d_in[9];
    const float* sage_wl = (const float*)d_in[10];
    const float* sage_bl = (const float*)d_in[11];
    const float* sage_wr = (const float*)d_in[12];
    const float* bn2g = (const float*)d_in[13], *bn2b = (const float*)d_in[14];
    const float* bn2m = (const float*)d_in[15], *bn2v = (const float*)d_in[16];
    const float* gcn_w = (const float*)d_in[17];
    const float* gcn_b = (const float*)d_in[18];
    const float* bn3g = (const float*)d_in[19], *bn3b = (const float*)d_in[20];
    const float* bn3m = (const float*)d_in[21], *bn3v = (const float*)d_in[22];

    const int* src  = ei;
    const int* dstp = ei + EE;

    char* W = (char*)d_ws;
    ushort* xw_h   = (ushort*)W;                       // N*128 bf16
    ushort* h1_h   = xw_h + (size_t)NN*128;            // N*128 bf16
    ushort* mean_h = h1_h + (size_t)NN*128;            // N*128 bf16
    ushort* hw_h   = mean_h + (size_t)NN*128;          // N*32 bf16
    float* a_s  = (float*)(hw_h + (size_t)NN*32 + 8192); // slack for OOB tile reads
    float* a_d  = a_s + (size_t)NN*4;
    float* dinv = a_d + (size_t)NN*4;
    int* row_ptr = (int*)(dinv + NN);                  // N+1
    int* counts  = row_ptr + (NN+1);                   // N (also cursor)
    int* col     = counts + NN;                        // E
    int* bsum    = col + EE;                           // NB1
    int* ebsum   = bsum + NB1;                         // 257
    ushort* wcat_h = (ushort*)(ebsum + 260);           // 64*256 bf16
    ushort* gcb_h  = wcat_h + 16384;                   // 32*64 bf16

    const uint* xw_u   = (const uint*)xw_h;
    const uint* h1_u   = (const uint*)h1_h;
    uint* mean_u = (uint*)mean_h;
    uint* hw_u   = (uint*)hw_h;
    const uint* wcat_u = (const uint*)wcat_h;
    const uint* gcb_u  = (const uint*)gcb_h;
    float* out = (float*)d_out;

    hipMemsetAsync(counts, 0, NN*sizeof(int), stream);
    k_count<<<(EE+255)/256, 256, 0, stream>>>(dstp, counts);
    k_bsum<<<NB1, 256, 0, stream>>>(counts, bsum);
    k_scan2<<<1, 256, 0, stream>>>(bsum, ebsum);
    k_rowptr<<<NB1, 256, 0, stream>>>(counts, ebsum, row_ptr);
    hipMemsetAsync(counts, 0, NN*sizeof(int), stream);
    k_scatter<<<(EE+255)/256, 256, 0, stream>>>(src, dstp, row_ptr, counts, col);
    k_dinv<<<(NN+255)/256, 256, 0, stream>>>(row_ptr, dinv);
    k_wprep<<<64, 256, 0, stream>>>(sage_wl, sage_wr, gcn_w, wcat_h, gcb_h);

    k_xw_mfma<<<XTILE, 256, 0, stream>>>(x, gat_w, att_s, att_d, xw_h, a_s, a_d);
    k_gat<<<2048, 256, 0, stream>>>(row_ptr, col, a_s, a_d, xw_u, gat_b,
                                    bn1g, bn1b, bn1m, bn1v, h1_h);
    k_mean<<<2048, 256, 0, stream>>>(row_ptr, col, h1_u, mean_u);
    k_sage_mfma<<<STILE, 256, 0, stream>>>(mean_u, h1_u, wcat_u, sage_bl, gcb_u,
                                           bn2g, bn2b, bn2m, bn2v, hw_h);
    k_gcn<<<NN/4, 256, 0, stream>>>(row_ptr, col, hw_u, dinv, gcn_b,
                                    bn3g, bn3b, bn3m, bn3v, out);
}